// Round 9
// baseline (1141.969 us; speedup 1.0000x reference)
//
#include <hip/hip_runtime.h>
#include <math.h>

#define NN 100000
#define NE 1600000
#define NG 64

typedef unsigned short u16;
typedef unsigned int u32;
typedef __attribute__((ext_vector_type(8))) short short8;   // 8 bf16 = 4 VGPR
typedef __attribute__((ext_vector_type(4))) float f32x4;    // MFMA C/D

__device__ __forceinline__ float gelu_f(float x) {
    return 0.5f * x * (1.0f + erff(x * 0.7071067811865475f));
}
// round-to-nearest-even fp32 -> bf16
__device__ __forceinline__ u16 f2bf(float f) {
    u32 u = __float_as_uint(f);
    u32 r = u + 0x7FFFu + ((u >> 16) & 1u);
    return (u16)(r >> 16);
}
__device__ __forceinline__ float bf2f(u16 h) { return __uint_as_float(((u32)h) << 16); }
// packed hi/lo bf16 pair in one u32: value ~= hi + lo, rel err ~2^-18
__device__ __forceinline__ u32 packf(float v) {
    u16 h = f2bf(v);
    u16 l = f2bf(v - bf2f(h));
    return (((u32)h) << 16) | (u32)l;
}
__device__ __forceinline__ float unpackf(u32 p) {
    return __uint_as_float(p & 0xFFFF0000u) + __uint_as_float(p << 16);
}
// 8 packed elems (2 uint4) -> hi/lo short8 for MFMA A-operand
__device__ __forceinline__ void unpack8(uint4 q0, uint4 q1, short8& hi, short8& lo) {
    u32 v[8] = {q0.x, q0.y, q0.z, q0.w, q1.x, q1.y, q1.z, q1.w};
#pragma unroll
    for (int e = 0; e < 8; ++e) {
        hi[e] = (short)(v[e] >> 16);
        lo[e] = (short)(v[e] & 0xFFFFu);
    }
}
// 8 fp32 elems (2 float4) -> hi/lo short8
__device__ __forceinline__ void cvt8f(float4 f0, float4 f1, short8& hi, short8& lo) {
    float v[8] = {f0.x, f0.y, f0.z, f0.w, f1.x, f1.y, f1.z, f1.w};
#pragma unroll
    for (int e = 0; e < 8; ++e) {
        u16 h = f2bf(v[e]);
        hi[e] = (short)h;
        lo[e] = (short)f2bf(v[e] - bf2f(h));
    }
}
#define MFMA __builtin_amdgcn_mfma_f32_16x16x32_bf16

// ---------------- CSR build ----------------
__global__ void k_hist(const int* __restrict__ dstp, int* __restrict__ cnt) {
    int e = blockIdx.x * 256 + threadIdx.x;
    if (e < NE) atomicAdd(&cnt[dstp[e]], 1);
}

#define SB 1024
__global__ __launch_bounds__(SB) void k_scan1(const int* __restrict__ cnt, int* __restrict__ rowp,
                                              int* __restrict__ blksum) {
    __shared__ int s[SB];
    int tid = threadIdx.x;
    int i = blockIdx.x * SB + tid;
    int v = (i < NN) ? cnt[i] : 0;
    int run = v;
    s[tid] = v;
    __syncthreads();
    for (int off = 1; off < SB; off <<= 1) {
        int t = (tid >= off) ? s[tid - off] : 0;
        __syncthreads();
        run += t;
        s[tid] = run;
        __syncthreads();
    }
    if (i < NN) rowp[i] = run - v;
    if (tid == SB - 1) blksum[blockIdx.x] = run;
}

__global__ void k_scan2(const int* __restrict__ blksum, int* __restrict__ blkoff, int nb) {
    __shared__ int s[128];
    int tid = threadIdx.x;
    int v = (tid < nb) ? blksum[tid] : 0;
    int run = v;
    s[tid] = v;
    __syncthreads();
    for (int off = 1; off < 128; off <<= 1) {
        int t = (tid >= off) ? s[tid - off] : 0;
        __syncthreads();
        run += t;
        s[tid] = run;
        __syncthreads();
    }
    if (tid < nb) blkoff[tid] = run - v;
}

__global__ void k_scan3(int* __restrict__ rowp, const int* __restrict__ blkoff) {
    int i = blockIdx.x * 256 + threadIdx.x;
    if (i < NN) rowp[i] += blkoff[i >> 10];
    else if (i == NN) rowp[NN] = NE;
}

__global__ void k_scatter(const int* __restrict__ srcp, const int* __restrict__ dstp,
                          const int* __restrict__ rowp, int* __restrict__ fill,
                          int* __restrict__ cidx) {
    int e = blockIdx.x * 256 + threadIdx.x;
    if (e < NE) {
        int d = dstp[e];
        int pos = atomicAdd(&fill[d], 1);
        cidx[rowp[d] + pos] = srcp[e];
    }
}

// ---------------- XCD-sliced mean-aggregate ----------------
// Feature dim split into 16 slices of 8 u32 cols (3.2MB/slice -> fits one XCD's
// 4MB L2). Slice is pinned to an XCD via the round-robin blockIdx%8 dispatch:
// blocks [0,25000) do slices 0-7 (s = b%8), blocks [25000,50000) do slices 8-15.
// Each XCD streams its slice from L3 once, then gathers L2-hit -> breaks the
// 8x-XCD-duplication floor (377MB -> ~205MB L2-miss/layer). Correctness does NOT
// depend on the mapping (any block order gives the same result).
// Block: 256 threads = 32 dst-nodes x 8 lanes (lane covers slice cols).
template <int PACKED>
__global__ __launch_bounds__(256) void k_agg(const void* __restrict__ xin, const int* __restrict__ rowp,
                                             const int* __restrict__ cidx, u32* __restrict__ agg) {
    int b = blockIdx.x;
    int s, tile;
    if (b < 25000) { s = b & 7;       tile = b >> 3; }
    else           { b -= 25000; s = 8 + (b & 7); tile = b >> 3; }
    int t = threadIdx.x;
    int node = tile * 32 + (t >> 3);
    int l8 = t & 7;
    if (node >= NN) return;
    int beg = rowp[node], endp = rowp[node + 1];
    int coloff = s * 8 + l8;
    const u32* xp = (const u32*)xin + coloff;
    const float* xf = (const float*)xin + coloff;
    float sum = 0.f;
    int e = beg;
    for (; e + 7 < endp; e += 8) {
        int i0 = cidx[e],     i1 = cidx[e + 1], i2 = cidx[e + 2], i3 = cidx[e + 3];
        int i4 = cidx[e + 4], i5 = cidx[e + 5], i6 = cidx[e + 6], i7 = cidx[e + 7];
        if (PACKED) {
            u32 v0 = xp[(size_t)i0 * 128], v1 = xp[(size_t)i1 * 128];
            u32 v2 = xp[(size_t)i2 * 128], v3 = xp[(size_t)i3 * 128];
            u32 v4 = xp[(size_t)i4 * 128], v5 = xp[(size_t)i5 * 128];
            u32 v6 = xp[(size_t)i6 * 128], v7 = xp[(size_t)i7 * 128];
            sum += ((unpackf(v0) + unpackf(v1)) + (unpackf(v2) + unpackf(v3))) +
                   ((unpackf(v4) + unpackf(v5)) + (unpackf(v6) + unpackf(v7)));
        } else {
            float v0 = xf[(size_t)i0 * 128], v1 = xf[(size_t)i1 * 128];
            float v2 = xf[(size_t)i2 * 128], v3 = xf[(size_t)i3 * 128];
            float v4 = xf[(size_t)i4 * 128], v5 = xf[(size_t)i5 * 128];
            float v6 = xf[(size_t)i6 * 128], v7 = xf[(size_t)i7 * 128];
            sum += ((v0 + v1) + (v2 + v3)) + ((v4 + v5) + (v6 + v7));
        }
    }
    for (; e < endp; ++e) {
        int i0 = cidx[e];
        sum += PACKED ? unpackf(xp[(size_t)i0 * 128]) : xf[(size_t)i0 * 128];
    }
    float inv = 1.0f / fmaxf((float)(endp - beg), 1.0f);
    agg[(size_t)node * 128 + coloff] = packf(sum * inv);
}

// ---------------- weight prep: transpose + bf16 hi/lo split (planes) ----------------
__global__ __launch_bounds__(256) void k_cvtw(const float* __restrict__ W0, const float* __restrict__ W1,
                                              const float* __restrict__ W2, const float* __restrict__ W3,
                                              const float* __restrict__ W4, u16* __restrict__ dst) {
    int idx = blockIdx.x * 256 + threadIdx.x;   // 5*16384
    int m = idx >> 14;
    int r = idx & 16383;
    int k = r >> 7, c = r & 127;
    const float* W = (m == 0) ? W0 : (m == 1) ? W1 : (m == 2) ? W2 : (m == 3) ? W3 : W4;
    float v = W[k * 128 + c];
    u16 h = f2bf(v);
    u16 l = f2bf(v - bf2f(h));
    u16* base = dst + (size_t)m * 32768;
    base[c * 128 + k] = h;
    base[16384 + c * 128 + k] = l;
}

// ---------------- fused SAGE layer via bf16x3 MFMA, A-prefetch pipelined ----------------
template <int A2F32>
__global__ __launch_bounds__(256) void k_sage_mf(const u32* A1, const u16* __restrict__ w1hi,
                                                 const u16* __restrict__ w1lo, const float* __restrict__ b1,
                                                 const void* A2v, const u16* __restrict__ w2hi,
                                                 const u16* __restrict__ w2lo, u32* out) {
    __shared__ u16 lds[4][128][40];
    const int t = threadIdx.x;
    const int lane = t & 63;
    const int w = t >> 6;
    const int l15 = lane & 15;
    const int lg = lane >> 4;
    const int n0 = blockIdx.x * 128 + w * 32;
    f32x4 acc[2][8];
#pragma unroll
    for (int ti = 0; ti < 2; ++ti)
#pragma unroll
        for (int ct = 0; ct < 8; ++ct) acc[ti][ct] = (f32x4){0.f, 0.f, 0.f, 0.f};
    int nA = n0 + l15;
    int nB = n0 + 16 + l15;
    if (nA >= NN) nA = NN - 1;
    if (nB >= NN) nB = NN - 1;
    const u32* a1A = A1 + (size_t)nA * 128;
    const u32* a1B = A1 + (size_t)nB * 128;
    const u32* a2Ap = (const u32*)A2v + (size_t)nA * 128;
    const u32* a2Bp = (const u32*)A2v + (size_t)nB * 128;
    const float* a2Af = (const float*)A2v + (size_t)nA * 128;
    const float* a2Bf = (const float*)A2v + (size_t)nB * 128;
    const int koff = 8 * lg;

    uint4 p1A[2][2], p1B[2][2];
    uint4 p2A[2][2], p2B[2][2];
    float4 f2A[2][2], f2B[2][2];

    {
        const uint4* q;
        q = (const uint4*)(a1A + koff); p1A[0][0] = q[0]; p1A[0][1] = q[1];
        q = (const uint4*)(a1B + koff); p1B[0][0] = q[0]; p1B[0][1] = q[1];
        if (A2F32) {
            const float4* f;
            f = (const float4*)(a2Af + koff); f2A[0][0] = f[0]; f2A[0][1] = f[1];
            f = (const float4*)(a2Bf + koff); f2B[0][0] = f[0]; f2B[0][1] = f[1];
        } else {
            q = (const uint4*)(a2Ap + koff); p2A[0][0] = q[0]; p2A[0][1] = q[1];
            q = (const uint4*)(a2Bp + koff); p2B[0][0] = q[0]; p2B[0][1] = q[1];
        }
    }
#pragma unroll
    for (int kb = 0; kb < 4; ++kb) {
        const int k0 = kb * 32;
        const int cur = kb & 1, nxt = cur ^ 1;
        __syncthreads();
#pragma unroll
        for (int u = 0; u < 2; ++u) {
            int unit = t + u * 256;
            int s = unit >> 7, c = unit & 127;
            const u16* src = (s == 0) ? w1hi : (s == 1) ? w1lo : (s == 2) ? w2hi : w2lo;
            const uint4* s4 = (const uint4*)(src + (size_t)c * 128 + k0);
            uint4* d4 = (uint4*)&lds[s][c][0];
            d4[0] = s4[0]; d4[1] = s4[1]; d4[2] = s4[2]; d4[3] = s4[3];
        }
        __syncthreads();
        if (kb < 3) {
            const int kn = k0 + 32 + koff;
            const uint4* q;
            q = (const uint4*)(a1A + kn); p1A[nxt][0] = q[0]; p1A[nxt][1] = q[1];
            q = (const uint4*)(a1B + kn); p1B[nxt][0] = q[0]; p1B[nxt][1] = q[1];
            if (A2F32) {
                const float4* f;
                f = (const float4*)(a2Af + kn); f2A[nxt][0] = f[0]; f2A[nxt][1] = f[1];
                f = (const float4*)(a2Bf + kn); f2B[nxt][0] = f[0]; f2B[nxt][1] = f[1];
            } else {
                q = (const uint4*)(a2Ap + kn); p2A[nxt][0] = q[0]; p2A[nxt][1] = q[1];
                q = (const uint4*)(a2Bp + kn); p2B[nxt][0] = q[0]; p2B[nxt][1] = q[1];
            }
        }
        short8 h1A, l1A, h1B, l1B, h2A, l2A, h2B, l2B;
        unpack8(p1A[cur][0], p1A[cur][1], h1A, l1A);
        unpack8(p1B[cur][0], p1B[cur][1], h1B, l1B);
        if (A2F32) {
            cvt8f(f2A[cur][0], f2A[cur][1], h2A, l2A);
            cvt8f(f2B[cur][0], f2B[cur][1], h2B, l2B);
        } else {
            unpack8(p2A[cur][0], p2A[cur][1], h2A, l2A);
            unpack8(p2B[cur][0], p2B[cur][1], h2B, l2B);
        }
#pragma unroll
        for (int ct = 0; ct < 8; ++ct) {
            int c = ct * 16 + l15;
            short8 bh1 = *(const short8*)&lds[0][c][koff];
            short8 bl1 = *(const short8*)&lds[1][c][koff];
            short8 bh2 = *(const short8*)&lds[2][c][koff];
            short8 bl2 = *(const short8*)&lds[3][c][koff];
            acc[0][ct] = MFMA(h1A, bh1, acc[0][ct], 0, 0, 0);
            acc[0][ct] = MFMA(l1A, bh1, acc[0][ct], 0, 0, 0);
            acc[0][ct] = MFMA(h1A, bl1, acc[0][ct], 0, 0, 0);
            acc[0][ct] = MFMA(h2A, bh2, acc[0][ct], 0, 0, 0);
            acc[0][ct] = MFMA(l2A, bh2, acc[0][ct], 0, 0, 0);
            acc[0][ct] = MFMA(h2A, bl2, acc[0][ct], 0, 0, 0);
            acc[1][ct] = MFMA(h1B, bh1, acc[1][ct], 0, 0, 0);
            acc[1][ct] = MFMA(l1B, bh1, acc[1][ct], 0, 0, 0);
            acc[1][ct] = MFMA(h1B, bl1, acc[1][ct], 0, 0, 0);
            acc[1][ct] = MFMA(h2B, bh2, acc[1][ct], 0, 0, 0);
            acc[1][ct] = MFMA(l2B, bh2, acc[1][ct], 0, 0, 0);
            acc[1][ct] = MFMA(h2B, bl2, acc[1][ct], 0, 0, 0);
        }
    }
#pragma unroll
    for (int ti = 0; ti < 2; ++ti) {
#pragma unroll
        for (int ct = 0; ct < 8; ++ct) {
            int c = ct * 16 + l15;
            float bb = b1[c];
#pragma unroll
            for (int r = 0; r < 4; ++r) {
                int node = n0 + ti * 16 + lg * 4 + r;
                if (node < NN) out[(size_t)node * 128 + c] = packf(gelu_f(acc[ti][ct][r] + bb));
            }
        }
    }
}

// ---------------- fused gate via bf16x3 MFMA (packed H input) ----------------
__global__ __launch_bounds__(256) void k_gatef_mf(const u32* __restrict__ H, const u16* __restrict__ wghi,
                                                   const u16* __restrict__ wglo, const float* __restrict__ bg1,
                                                   const float* __restrict__ Wg2, float* __restrict__ gate) {
    __shared__ u16 lds[2][128][40];
    const int t = threadIdx.x;
    const int lane = t & 63;
    const int w = t >> 6;
    const int l15 = lane & 15;
    const int lg = lane >> 4;
    const int n0 = blockIdx.x * 128 + w * 32;
    f32x4 acc[2][8];
#pragma unroll
    for (int ti = 0; ti < 2; ++ti)
#pragma unroll
        for (int ct = 0; ct < 8; ++ct) acc[ti][ct] = (f32x4){0.f, 0.f, 0.f, 0.f};
    int nA = n0 + l15;
    int nB = n0 + 16 + l15;
    if (nA >= NN) nA = NN - 1;
    if (nB >= NN) nB = NN - 1;
    const u32* hA = H + (size_t)nA * 128;
    const u32* hB = H + (size_t)nB * 128;
    const int koff = 8 * lg;
    uint4 pA[2][2], pB[2][2];
    {
        const uint4* q;
        q = (const uint4*)(hA + koff); pA[0][0] = q[0]; pA[0][1] = q[1];
        q = (const uint4*)(hB + koff); pB[0][0] = q[0]; pB[0][1] = q[1];
    }
#pragma unroll
    for (int kb = 0; kb < 4; ++kb) {
        const int k0 = kb * 32;
        const int cur = kb & 1, nxt = cur ^ 1;
        __syncthreads();
        if (t < 256) {
            int s = t >> 7, c = t & 127;
            const u16* src = (s == 0) ? wghi : wglo;
            const uint4* s4 = (const uint4*)(src + (size_t)c * 128 + k0);
            uint4* d4 = (uint4*)&lds[s][c][0];
            d4[0] = s4[0]; d4[1] = s4[1]; d4[2] = s4[2]; d4[3] = s4[3];
        }
        __syncthreads();
        if (kb < 3) {
            const int kn = k0 + 32 + koff;
            const uint4* q;
            q = (const uint4*)(hA + kn); pA[nxt][0] = q[0]; pA[nxt][1] = q[1];
            q = (const uint4*)(hB + kn); pB[nxt][0] = q[0]; pB[nxt][1] = q[1];
        }
        short8 hAh, hAl, hBh, hBl;
        unpack8(pA[cur][0], pA[cur][1], hAh, hAl);
        unpack8(pB[cur][0], pB[cur][1], hBh, hBl);
#pragma unroll
        for (int ct = 0; ct < 8; ++ct) {
            int c = ct * 16 + l15;
            short8 bh = *(const short8*)&lds[0][c][koff];
            short8 bl = *(const short8*)&lds[1][c][koff];
            acc[0][ct] = MFMA(hAh, bh, acc[0][ct], 0, 0, 0);
            acc[0][ct] = MFMA(hAl, bh, acc[0][ct], 0, 0, 0);
            acc[0][ct] = MFMA(hAh, bl, acc[0][ct], 0, 0, 0);
            acc[1][ct] = MFMA(hBh, bh, acc[1][ct], 0, 0, 0);
            acc[1][ct] = MFMA(hBl, bh, acc[1][ct], 0, 0, 0);
            acc[1][ct] = MFMA(hBh, bl, acc[1][ct], 0, 0, 0);
        }
    }
    float p[2][4];
#pragma unroll
    for (int ti = 0; ti < 2; ++ti)
#pragma unroll
        for (int r = 0; r < 4; ++r) p[ti][r] = 0.f;
#pragma unroll
    for (int ct = 0; ct < 8; ++ct) {
        int c = ct * 16 + l15;
        float bb = bg1[c];
        float gv = Wg2[c];
#pragma unroll
        for (int ti = 0; ti < 2; ++ti)
#pragma unroll
            for (int r = 0; r < 4; ++r) p[ti][r] += gelu_f(acc[ti][ct][r] + bb) * gv;
    }
#pragma unroll
    for (int m = 1; m < 16; m <<= 1) {
#pragma unroll
        for (int ti = 0; ti < 2; ++ti)
#pragma unroll
            for (int r = 0; r < 4; ++r) p[ti][r] += __shfl_xor(p[ti][r], m);
    }
    if (l15 == 0) {
#pragma unroll
        for (int ti = 0; ti < 2; ++ti)
#pragma unroll
            for (int r = 0; r < 4; ++r) {
                int node = n0 + ti * 16 + lg * 4 + r;
                if (node < NN) gate[node] = p[ti][r];
            }
    }
}

// ---------------- pooling stage 1 ----------------
__global__ __launch_bounds__(256) void k_pstats(const float* __restrict__ gate, const int* __restrict__ batch,
                                                float* __restrict__ gm, float* __restrict__ gden) {
    int g = blockIdx.x;
    int lo = 0, hi = NN;
    while (lo < hi) { int mid = (lo + hi) >> 1; if (batch[mid] < g) lo = mid + 1; else hi = mid; }
    int start = lo;
    lo = start; hi = NN;
    while (lo < hi) { int mid = (lo + hi) >> 1; if (batch[mid] < g + 1) lo = mid + 1; else hi = mid; }
    int endp = lo;

    __shared__ float red[256];
    int tid = threadIdx.x;

    float m = -1e30f;
    for (int i = start + tid; i < endp; i += 256) m = fmaxf(m, gate[i]);
    red[tid] = m;
    __syncthreads();
    for (int off = 128; off; off >>= 1) {
        if (tid < off) red[tid] = fmaxf(red[tid], red[tid + off]);
        __syncthreads();
    }
    m = red[0];
    __syncthreads();

    float s = 0.f;
    for (int i = start + tid; i < endp; i += 256) s += expf(gate[i] - m);
    red[tid] = s;
    __syncthreads();
    for (int off = 128; off; off >>= 1) {
        if (tid < off) red[tid] += red[tid + off];
        __syncthreads();
    }
    if (tid == 0) { gm[g] = m; gden[g] = red[0]; }
}

// ---------------- pooling stage 2 (packed H) ----------------
__global__ __launch_bounds__(256) void k_pacc(const u32* __restrict__ H, const float* __restrict__ gate,
                                              const int* __restrict__ batch, const float* __restrict__ gm,
                                              const float* __restrict__ gden, float* __restrict__ gacc) {
    int c = threadIdx.x & 127;
    int h = threadIdx.x >> 7;
    int n0 = blockIdx.x * 128;
    int nend = n0 + 128;
    if (nend > NN) nend = NN;
    int i = n0 + h;
    if (i >= nend) return;
    int cur = batch[i];
    float m = gm[cur], invd = 1.0f / gden[cur];
    float acc = 0.f;
    for (; i < nend; i += 2) {
        int gi = batch[i];
        if (gi != cur) {
            atomicAdd(&gacc[cur * 128 + c], acc * invd);
            acc = 0.f;
            cur = gi;
            m = gm[cur];
            invd = 1.0f / gden[cur];
        }
        acc = fmaf(expf(gate[i] - m), unpackf(H[(size_t)i * 128 + c]), acc);
    }
    atomicAdd(&gacc[cur * 128 + c], acc * invd);
}

// ---------------- head ----------------
__global__ __launch_bounds__(64) void k_head(const float* __restrict__ gacc, const float* __restrict__ Wh,
                                             const float* __restrict__ bh, float* __restrict__ out) {
    int g = blockIdx.x;
    int l = threadIdx.x;
    float v = gacc[g * 128 + l] * Wh[l] + gacc[g * 128 + 64 + l] * Wh[64 + l];
#pragma unroll
    for (int m = 1; m < 64; m <<= 1) v += __shfl_xor(v, m);
    if (l == 0) out[g] = v + bh[0];
}

extern "C" void kernel_launch(void* const* d_in, const int* in_sizes, int n_in,
                              void* d_out, int out_size, void* d_ws, size_t ws_size,
                              hipStream_t stream) {
    (void)in_sizes; (void)n_in; (void)out_size; (void)ws_size;
    const float* x   = (const float*)d_in[0];
    const int*  ei   = (const int*)d_in[1];
    const int*  batch= (const int*)d_in[2];
    const float* Wl0 = (const float*)d_in[3];
    const float* bl0 = (const float*)d_in[4];
    const float* Wr0 = (const float*)d_in[5];
    const float* Wl1 = (const float*)d_in[6];
    const float* bl1 = (const float*)d_in[7];
    const float* Wr1 = (const float*)d_in[8];
    const float* Wg1 = (const float*)d_in[9];
    const float* bg1 = (const float*)d_in[10];
    const float* Wg2 = (const float*)d_in[11];
    const float* Wh  = (const float*)d_in[13];
    const float* bh  = (const float*)d_in[14];
    float* out = (float*)d_out;

    const int* srcp = ei;
    const int* dstp = ei + NE;

    char* w = (char*)d_ws;
    size_t off = 0;
    auto alloc = [&](size_t bytes) { void* p = w + off; off += (bytes + 255) & ~(size_t)255; return p; };
    u32* AGG   = (u32*)alloc((size_t)NN * 128 * 4);  // packed agg / h2 (in-place)
    u32* H1    = (u32*)alloc((size_t)NN * 128 * 4);  // packed h1
    float* gate  = (float*)alloc((size_t)NN * 4);
    int* cnt     = (int*)alloc((size_t)NN * 4);
    int* rowp    = (int*)alloc((size_t)(NN + 1) * 4);
    int* fill    = (int*)alloc((size_t)NN * 4);
    int* cidx    = (int*)alloc((size_t)NE * 4);
    int* blksum  = (int*)alloc(128 * 4);
    int* blkoff  = (int*)alloc(128 * 4);
    float* gm    = (float*)alloc(NG * 4);
    float* gden  = (float*)alloc(NG * 4);
    float* gacc  = (float*)alloc((size_t)NG * 128 * 4);
    u16* wt      = (u16*)alloc((size_t)5 * 32768 * 2);   // 5 mats x (hi|lo) [c][k] bf16

    hipMemsetAsync(cnt, 0, (size_t)NN * 4, stream);
    hipMemsetAsync(fill, 0, (size_t)NN * 4, stream);
    hipMemsetAsync(gacc, 0, (size_t)NG * 128 * 4, stream);

    // weight transpose + bf16 hi/lo split (mat order: Wl0, Wr0, Wl1, Wr1, Wg1)
    k_cvtw<<<320, 256, 0, stream>>>(Wl0, Wr0, Wl1, Wr1, Wg1, wt);

    // CSR build (reused by both layers)
    k_hist<<<(NE + 255) / 256, 256, 0, stream>>>(dstp, cnt);
    int nb = (NN + SB - 1) / SB;
    k_scan1<<<nb, SB, 0, stream>>>(cnt, rowp, blksum);
    k_scan2<<<1, 128, 0, stream>>>(blksum, blkoff, nb);
    k_scan3<<<(NN + 1 + 255) / 256, 256, 0, stream>>>(rowp, blkoff);
    k_scatter<<<(NE + 255) / 256, 256, 0, stream>>>(srcp, dstp, rowp, fill, cidx);

    int gs = (NN + 127) / 128;           // 782 MFMA-GEMM blocks (128-node tiles)
    int ga = 50000;                      // sliced agg: 16 slices x 3125 dst-tiles
    u16* Wl0hi = wt;
    u16* Wl0lo = wt + 16384;
    u16* Wr0hi = wt + 32768;
    u16* Wr0lo = wt + 49152;
    u16* Wl1hi = wt + 65536;
    u16* Wl1lo = wt + 81920;
    u16* Wr1hi = wt + 98304;
    u16* Wr1lo = wt + 114688;
    u16* Wg1hi = wt + 131072;
    u16* Wg1lo = wt + 147456;
    // layer 0: agg from fp32 x; root A2 = fp32 x
    k_agg<0><<<ga, 256, 0, stream>>>(x, rowp, cidx, AGG);
    k_sage_mf<1><<<gs, 256, 0, stream>>>(AGG, Wl0hi, Wl0lo, bl0, x, Wr0hi, Wr0lo, H1);
    // layer 1: agg from packed h1; root A2 = packed h1; h2 in-place over AGG
    k_agg<1><<<ga, 256, 0, stream>>>(H1, rowp, cidx, AGG);
    k_sage_mf<0><<<gs, 256, 0, stream>>>(AGG, Wl1hi, Wl1lo, bl1, H1, Wr1hi, Wr1lo, AGG);
    // gate + pool + head (H = packed h2 in AGG)
    k_gatef_mf<<<gs, 256, 0, stream>>>(AGG, Wg1hi, Wg1lo, bg1, Wg2, gate);
    k_pstats<<<NG, 256, 0, stream>>>(gate, batch, gm, gden);
    k_pacc<<<(NN + 127) / 128, 256, 0, stream>>>(AGG, gate, batch, gm, gden, gacc);
    k_head<<<NG, 64, 0, stream>>>(gacc, Wh, bh, out);
}

// Round 10
// 776.742 us; speedup vs baseline: 1.4702x; 1.4702x over previous
//
#include <hip/hip_runtime.h>
#include <math.h>

#define NN 100000
#define NE 1600000
#define NG 64

typedef unsigned short u16;
typedef unsigned int u32;
typedef __attribute__((ext_vector_type(8))) short short8;   // 8 bf16 = 4 VGPR
typedef __attribute__((ext_vector_type(4))) float f32x4;    // MFMA C/D

__device__ __forceinline__ float gelu_f(float x) {
    return 0.5f * x * (1.0f + erff(x * 0.7071067811865475f));
}
// round-to-nearest-even fp32 -> bf16
__device__ __forceinline__ u16 f2bf(float f) {
    u32 u = __float_as_uint(f);
    u32 r = u + 0x7FFFu + ((u >> 16) & 1u);
    return (u16)(r >> 16);
}
__device__ __forceinline__ float bf2f(u16 h) { return __uint_as_float(((u32)h) << 16); }
// packed hi/lo bf16 pair in one u32: value ~= hi + lo, rel err ~2^-18
__device__ __forceinline__ u32 packf(float v) {
    u16 h = f2bf(v);
    u16 l = f2bf(v - bf2f(h));
    return (((u32)h) << 16) | (u32)l;
}
__device__ __forceinline__ float unpackf(u32 p) {
    return __uint_as_float(p & 0xFFFF0000u) + __uint_as_float(p << 16);
}
// 8 packed elems (2 uint4) -> hi/lo short8 for MFMA A-operand
__device__ __forceinline__ void unpack8(uint4 q0, uint4 q1, short8& hi, short8& lo) {
    u32 v[8] = {q0.x, q0.y, q0.z, q0.w, q1.x, q1.y, q1.z, q1.w};
#pragma unroll
    for (int e = 0; e < 8; ++e) {
        hi[e] = (short)(v[e] >> 16);
        lo[e] = (short)(v[e] & 0xFFFFu);
    }
}
// 8 fp32 elems (2 float4) -> hi/lo short8
__device__ __forceinline__ void cvt8f(float4 f0, float4 f1, short8& hi, short8& lo) {
    float v[8] = {f0.x, f0.y, f0.z, f0.w, f1.x, f1.y, f1.z, f1.w};
#pragma unroll
    for (int e = 0; e < 8; ++e) {
        u16 h = f2bf(v[e]);
        hi[e] = (short)h;
        lo[e] = (short)f2bf(v[e] - bf2f(h));
    }
}
#define MFMA __builtin_amdgcn_mfma_f32_16x16x32_bf16

// ---------------- CSR build ----------------
__global__ void k_hist(const int* __restrict__ dstp, int* __restrict__ cnt) {
    int e = blockIdx.x * 256 + threadIdx.x;
    if (e < NE) atomicAdd(&cnt[dstp[e]], 1);
}

#define SB 1024
__global__ __launch_bounds__(SB) void k_scan1(const int* __restrict__ cnt, int* __restrict__ rowp,
                                              int* __restrict__ blksum) {
    __shared__ int s[SB];
    int tid = threadIdx.x;
    int i = blockIdx.x * SB + tid;
    int v = (i < NN) ? cnt[i] : 0;
    int run = v;
    s[tid] = v;
    __syncthreads();
    for (int off = 1; off < SB; off <<= 1) {
        int t = (tid >= off) ? s[tid - off] : 0;
        __syncthreads();
        run += t;
        s[tid] = run;
        __syncthreads();
    }
    if (i < NN) rowp[i] = run - v;
    if (tid == SB - 1) blksum[blockIdx.x] = run;
}

__global__ void k_scan2(const int* __restrict__ blksum, int* __restrict__ blkoff, int nb) {
    __shared__ int s[128];
    int tid = threadIdx.x;
    int v = (tid < nb) ? blksum[tid] : 0;
    int run = v;
    s[tid] = v;
    __syncthreads();
    for (int off = 1; off < 128; off <<= 1) {
        int t = (tid >= off) ? s[tid - off] : 0;
        __syncthreads();
        run += t;
        s[tid] = run;
        __syncthreads();
    }
    if (tid < nb) blkoff[tid] = run - v;
}

__global__ void k_scan3(int* __restrict__ rowp, const int* __restrict__ blkoff) {
    int i = blockIdx.x * 256 + threadIdx.x;
    if (i < NN) rowp[i] += blkoff[i >> 10];
    else if (i == NN) rowp[NN] = NE;
}

__global__ void k_scatter(const int* __restrict__ srcp, const int* __restrict__ dstp,
                          const int* __restrict__ rowp, int* __restrict__ fill,
                          int* __restrict__ cidx) {
    int e = blockIdx.x * 256 + threadIdx.x;
    if (e < NE) {
        int d = dstp[e];
        int pos = atomicAdd(&fill[d], 1);
        cidx[rowp[d] + pos] = srcp[e];
    }
}

// ---------------- weight prep: transpose + bf16 hi/lo split (planes) ----------------
__global__ __launch_bounds__(256) void k_cvtw(const float* __restrict__ W0, const float* __restrict__ W1,
                                              const float* __restrict__ W2, const float* __restrict__ W3,
                                              const float* __restrict__ W4, u16* __restrict__ dst) {
    int idx = blockIdx.x * 256 + threadIdx.x;   // 5*16384
    int m = idx >> 14;
    int r = idx & 16383;
    int k = r >> 7, c = r & 127;
    const float* W = (m == 0) ? W0 : (m == 1) ? W1 : (m == 2) ? W2 : (m == 3) ? W3 : W4;
    float v = W[k * 128 + c];
    u16 h = f2bf(v);
    u16 l = f2bf(v - bf2f(h));
    u16* base = dst + (size_t)m * 32768;
    base[c * 128 + k] = h;
    base[16384 + c * 128 + k] = l;
}

// ---------------- FUSED mean-aggregate + SAGE layer (bf16x3 MFMA) ----------------
// out = gelu(mean_{j in N(i)} X_j @ W1 + b1 + X_i @ W2), X fp32 (XF32=1) or packed.
// Output packed u32. 256 thr = 4 waves; block = 64 nodes; wave = 16 nodes (1 M-tile).
// Phase 1: wave-uniform gather (one node at a time, 8 rows in flight, fp32 sums —
//   identical math to the r8 k_agg) -> packed mean into wave-private LDS aggT rows.
//   Saves the 51MB agg write + 51MB GEMM re-read per layer vs the split version.
// Phase 2: two passes (W1-stream from aggT/LDS, W2-stream root rows from global),
//   W k-slices staged per-stream in wlds[2][128][36] (72B stride = conflict-free-
//   floor b128 reads). aggT stride 132 u32: 16B-aligned rows, conflict-free floor.
// aggT rows are wave-private (no cross-wave barrier needed for them).
template <int XF32>
__global__ __launch_bounds__(256) void k_fsage(const void* __restrict__ X, const u16* __restrict__ w1hi,
                                               const u16* __restrict__ w1lo, const float* __restrict__ b1,
                                               const u16* __restrict__ w2hi, const u16* __restrict__ w2lo,
                                               const int* __restrict__ rowp, const int* __restrict__ cidx,
                                               u32* __restrict__ out) {
    __shared__ u32 aggT[64][132];        // 33.8 KB packed mean tile
    __shared__ u16 wlds[2][128][36];     // 18.4 KB W slice (hi|lo), per-stream
    const int t = threadIdx.x;
    const int lane = t & 63;
    const int w = t >> 6;
    const int l15 = lane & 15;
    const int lg = lane >> 4;
    const int nodeBase = blockIdx.x * 64 + w * 16;
    const int koff = 8 * lg;

    // ---- phase 1: gather means for this wave's 16 nodes ----
    for (int i = 0; i < 16; ++i) {
        int node = nodeBase + i;
        float s0 = 0.f, s1 = 0.f;
        if (node < NN) {
            int beg = rowp[node], endp = rowp[node + 1];
            int e = beg;
            for (; e + 7 < endp; e += 8) {
                int idx[8];
#pragma unroll
                for (int u = 0; u < 8; ++u) idx[u] = cidx[e + u];
                if (XF32) {
                    float2 v[8];
#pragma unroll
                    for (int u = 0; u < 8; ++u) v[u] = ((const float2*)X)[(size_t)idx[u] * 64 + lane];
#pragma unroll
                    for (int u = 0; u < 8; ++u) { s0 += v[u].x; s1 += v[u].y; }
                } else {
                    uint2 q[8];
#pragma unroll
                    for (int u = 0; u < 8; ++u) q[u] = ((const uint2*)X)[(size_t)idx[u] * 64 + lane];
#pragma unroll
                    for (int u = 0; u < 8; ++u) { s0 += unpackf(q[u].x); s1 += unpackf(q[u].y); }
                }
            }
            for (; e < endp; ++e) {
                int i0 = cidx[e];
                if (XF32) {
                    float2 v = ((const float2*)X)[(size_t)i0 * 64 + lane];
                    s0 += v.x; s1 += v.y;
                } else {
                    uint2 q = ((const uint2*)X)[(size_t)i0 * 64 + lane];
                    s0 += unpackf(q.x); s1 += unpackf(q.y);
                }
            }
            float inv = 1.0f / fmaxf((float)(endp - beg), 1.0f);
            s0 *= inv; s1 *= inv;
        }
        aggT[w * 16 + i][2 * lane]     = packf(s0);
        aggT[w * 16 + i][2 * lane + 1] = packf(s1);
    }

    f32x4 acc[8];
#pragma unroll
    for (int ct = 0; ct < 8; ++ct) acc[ct] = (f32x4){0.f, 0.f, 0.f, 0.f};

    // ---- phase 2a: W1 stream, A from aggT (LDS) ----
#pragma unroll
    for (int kb = 0; kb < 4; ++kb) {
        const int k0 = kb * 32;
        __syncthreads();
        {   // stage W1 hi|lo k-slice: 256 units of 64B
            int s = t >> 7, c = t & 127;
            const u16* src = s ? w1lo : w1hi;
            const uint4* s4 = (const uint4*)(src + (size_t)c * 128 + k0);
            uint4* d4 = (uint4*)&wlds[s][c][0];
            d4[0] = s4[0]; d4[1] = s4[1]; d4[2] = s4[2]; d4[3] = s4[3];
        }
        __syncthreads();
        const u32* arow = &aggT[w * 16 + l15][k0 + koff];
        uint4 q0 = *(const uint4*)arow;
        uint4 q1 = *(const uint4*)(arow + 4);
        short8 h1, l1;
        unpack8(q0, q1, h1, l1);
#pragma unroll
        for (int ct = 0; ct < 8; ++ct) {
            int c = ct * 16 + l15;
            short8 bh = *(const short8*)&wlds[0][c][koff];
            short8 bl = *(const short8*)&wlds[1][c][koff];
            acc[ct] = MFMA(h1, bh, acc[ct], 0, 0, 0);
            acc[ct] = MFMA(l1, bh, acc[ct], 0, 0, 0);
            acc[ct] = MFMA(h1, bl, acc[ct], 0, 0, 0);
        }
    }

    // ---- phase 2b: W2 stream, A = root rows from global (prefetched) ----
    int nR = nodeBase + l15;
    if (nR >= NN) nR = NN - 1;   // clamp loads; stores guarded below
    const u32* rp = (const u32*)X + (size_t)nR * 128;
    const float* rf = (const float*)X + (size_t)nR * 128;
    uint4 pq[2][2];
    float4 pf[2][2];
    if (XF32) {
        const float4* f = (const float4*)(rf + koff);
        pf[0][0] = f[0]; pf[0][1] = f[1];
    } else {
        const uint4* q = (const uint4*)(rp + koff);
        pq[0][0] = q[0]; pq[0][1] = q[1];
    }
#pragma unroll
    for (int kb = 0; kb < 4; ++kb) {
        const int k0 = kb * 32;
        const int cur = kb & 1, nxt = cur ^ 1;
        __syncthreads();
        {   // stage W2 hi|lo k-slice
            int s = t >> 7, c = t & 127;
            const u16* src = s ? w2lo : w2hi;
            const uint4* s4 = (const uint4*)(src + (size_t)c * 128 + k0);
            uint4* d4 = (uint4*)&wlds[s][c][0];
            d4[0] = s4[0]; d4[1] = s4[1]; d4[2] = s4[2]; d4[3] = s4[3];
        }
        __syncthreads();
        if (kb < 3) {
            const int kn = k0 + 32 + koff;
            if (XF32) {
                const float4* f = (const float4*)(rf + kn);
                pf[nxt][0] = f[0]; pf[nxt][1] = f[1];
            } else {
                const uint4* q = (const uint4*)(rp + kn);
                pq[nxt][0] = q[0]; pq[nxt][1] = q[1];
            }
        }
        short8 h2, l2;
        if (XF32) cvt8f(pf[cur][0], pf[cur][1], h2, l2);
        else      unpack8(pq[cur][0], pq[cur][1], h2, l2);
#pragma unroll
        for (int ct = 0; ct < 8; ++ct) {
            int c = ct * 16 + l15;
            short8 bh = *(const short8*)&wlds[0][c][koff];
            short8 bl = *(const short8*)&wlds[1][c][koff];
            acc[ct] = MFMA(h2, bh, acc[ct], 0, 0, 0);
            acc[ct] = MFMA(l2, bh, acc[ct], 0, 0, 0);
            acc[ct] = MFMA(h2, bl, acc[ct], 0, 0, 0);
        }
    }

    // ---- epilogue: D col = lane&15, row = (lane>>4)*4 + reg ----
#pragma unroll
    for (int ct = 0; ct < 8; ++ct) {
        int c = ct * 16 + l15;
        float bb = b1[c];
#pragma unroll
        for (int r = 0; r < 4; ++r) {
            int node = nodeBase + lg * 4 + r;
            if (node < NN) out[(size_t)node * 128 + c] = packf(gelu_f(acc[ct][r] + bb));
        }
    }
}

// ---------------- fused gate via bf16x3 MFMA (packed H input) ----------------
__global__ __launch_bounds__(256) void k_gatef_mf(const u32* __restrict__ H, const u16* __restrict__ wghi,
                                                   const u16* __restrict__ wglo, const float* __restrict__ bg1,
                                                   const float* __restrict__ Wg2, float* __restrict__ gate) {
    __shared__ u16 lds[2][128][40];
    const int t = threadIdx.x;
    const int lane = t & 63;
    const int w = t >> 6;
    const int l15 = lane & 15;
    const int lg = lane >> 4;
    const int n0 = blockIdx.x * 128 + w * 32;
    f32x4 acc[2][8];
#pragma unroll
    for (int ti = 0; ti < 2; ++ti)
#pragma unroll
        for (int ct = 0; ct < 8; ++ct) acc[ti][ct] = (f32x4){0.f, 0.f, 0.f, 0.f};
    int nA = n0 + l15;
    int nB = n0 + 16 + l15;
    if (nA >= NN) nA = NN - 1;
    if (nB >= NN) nB = NN - 1;
    const u32* hA = H + (size_t)nA * 128;
    const u32* hB = H + (size_t)nB * 128;
    const int koff = 8 * lg;
    uint4 pA[2][2], pB[2][2];
    {
        const uint4* q;
        q = (const uint4*)(hA + koff); pA[0][0] = q[0]; pA[0][1] = q[1];
        q = (const uint4*)(hB + koff); pB[0][0] = q[0]; pB[0][1] = q[1];
    }
#pragma unroll
    for (int kb = 0; kb < 4; ++kb) {
        const int k0 = kb * 32;
        const int cur = kb & 1, nxt = cur ^ 1;
        __syncthreads();
        if (t < 256) {
            int s = t >> 7, c = t & 127;
            const u16* src = (s == 0) ? wghi : wglo;
            const uint4* s4 = (const uint4*)(src + (size_t)c * 128 + k0);
            uint4* d4 = (uint4*)&lds[s][c][0];
            d4[0] = s4[0]; d4[1] = s4[1]; d4[2] = s4[2]; d4[3] = s4[3];
        }
        __syncthreads();
        if (kb < 3) {
            const int kn = k0 + 32 + koff;
            const uint4* q;
            q = (const uint4*)(hA + kn); pA[nxt][0] = q[0]; pA[nxt][1] = q[1];
            q = (const uint4*)(hB + kn); pB[nxt][0] = q[0]; pB[nxt][1] = q[1];
        }
        short8 hAh, hAl, hBh, hBl;
        unpack8(pA[cur][0], pA[cur][1], hAh, hAl);
        unpack8(pB[cur][0], pB[cur][1], hBh, hBl);
#pragma unroll
        for (int ct = 0; ct < 8; ++ct) {
            int c = ct * 16 + l15;
            short8 bh = *(const short8*)&lds[0][c][koff];
            short8 bl = *(const short8*)&lds[1][c][koff];
            acc[0][ct] = MFMA(hAh, bh, acc[0][ct], 0, 0, 0);
            acc[0][ct] = MFMA(hAl, bh, acc[0][ct], 0, 0, 0);
            acc[0][ct] = MFMA(hAh, bl, acc[0][ct], 0, 0, 0);
            acc[1][ct] = MFMA(hBh, bh, acc[1][ct], 0, 0, 0);
            acc[1][ct] = MFMA(hBl, bh, acc[1][ct], 0, 0, 0);
            acc[1][ct] = MFMA(hBh, bl, acc[1][ct], 0, 0, 0);
        }
    }
    float p[2][4];
#pragma unroll
    for (int ti = 0; ti < 2; ++ti)
#pragma unroll
        for (int r = 0; r < 4; ++r) p[ti][r] = 0.f;
#pragma unroll
    for (int ct = 0; ct < 8; ++ct) {
        int c = ct * 16 + l15;
        float bb = bg1[c];
        float gv = Wg2[c];
#pragma unroll
        for (int ti = 0; ti < 2; ++ti)
#pragma unroll
            for (int r = 0; r < 4; ++r) p[ti][r] += gelu_f(acc[ti][ct][r] + bb) * gv;
    }
#pragma unroll
    for (int m = 1; m < 16; m <<= 1) {
#pragma unroll
        for (int ti = 0; ti < 2; ++ti)
#pragma unroll
            for (int r = 0; r < 4; ++r) p[ti][r] += __shfl_xor(p[ti][r], m);
    }
    if (l15 == 0) {
#pragma unroll
        for (int ti = 0; ti < 2; ++ti)
#pragma unroll
            for (int r = 0; r < 4; ++r) {
                int node = n0 + ti * 16 + lg * 4 + r;
                if (node < NN) gate[node] = p[ti][r];
            }
    }
}

// ---------------- pooling stage 1 ----------------
__global__ __launch_bounds__(256) void k_pstats(const float* __restrict__ gate, const int* __restrict__ batch,
                                                float* __restrict__ gm, float* __restrict__ gden) {
    int g = blockIdx.x;
    int lo = 0, hi = NN;
    while (lo < hi) { int mid = (lo + hi) >> 1; if (batch[mid] < g) lo = mid + 1; else hi = mid; }
    int start = lo;
    lo = start; hi = NN;
    while (lo < hi) { int mid = (lo + hi) >> 1; if (batch[mid] < g + 1) lo = mid + 1; else hi = mid; }
    int endp = lo;

    __shared__ float red[256];
    int tid = threadIdx.x;

    float m = -1e30f;
    for (int i = start + tid; i < endp; i += 256) m = fmaxf(m, gate[i]);
    red[tid] = m;
    __syncthreads();
    for (int off = 128; off; off >>= 1) {
        if (tid < off) red[tid] = fmaxf(red[tid], red[tid + off]);
        __syncthreads();
    }
    m = red[0];
    __syncthreads();

    float s = 0.f;
    for (int i = start + tid; i < endp; i += 256) s += expf(gate[i] - m);
    red[tid] = s;
    __syncthreads();
    for (int off = 128; off; off >>= 1) {
        if (tid < off) red[tid] += red[tid + off];
        __syncthreads();
    }
    if (tid == 0) { gm[g] = m; gden[g] = red[0]; }
}

// ---------------- pooling stage 2 (packed H) ----------------
__global__ __launch_bounds__(256) void k_pacc(const u32* __restrict__ H, const float* __restrict__ gate,
                                              const int* __restrict__ batch, const float* __restrict__ gm,
                                              const float* __restrict__ gden, float* __restrict__ gacc) {
    int c = threadIdx.x & 127;
    int h = threadIdx.x >> 7;
    int n0 = blockIdx.x * 128;
    int nend = n0 + 128;
    if (nend > NN) nend = NN;
    int i = n0 + h;
    if (i >= nend) return;
    int cur = batch[i];
    float m = gm[cur], invd = 1.0f / gden[cur];
    float acc = 0.f;
    for (; i < nend; i += 2) {
        int gi = batch[i];
        if (gi != cur) {
            atomicAdd(&gacc[cur * 128 + c], acc * invd);
            acc = 0.f;
            cur = gi;
            m = gm[cur];
            invd = 1.0f / gden[cur];
        }
        acc = fmaf(expf(gate[i] - m), unpackf(H[(size_t)i * 128 + c]), acc);
    }
    atomicAdd(&gacc[cur * 128 + c], acc * invd);
}

// ---------------- head ----------------
__global__ __launch_bounds__(64) void k_head(const float* __restrict__ gacc, const float* __restrict__ Wh,
                                             const float* __restrict__ bh, float* __restrict__ out) {
    int g = blockIdx.x;
    int l = threadIdx.x;
    float v = gacc[g * 128 + l] * Wh[l] + gacc[g * 128 + 64 + l] * Wh[64 + l];
#pragma unroll
    for (int m = 1; m < 64; m <<= 1) v += __shfl_xor(v, m);
    if (l == 0) out[g] = v + bh[0];
}

extern "C" void kernel_launch(void* const* d_in, const int* in_sizes, int n_in,
                              void* d_out, int out_size, void* d_ws, size_t ws_size,
                              hipStream_t stream) {
    (void)in_sizes; (void)n_in; (void)out_size; (void)ws_size;
    const float* x   = (const float*)d_in[0];
    const int*  ei   = (const int*)d_in[1];
    const int*  batch= (const int*)d_in[2];
    const float* Wl0 = (const float*)d_in[3];
    const float* bl0 = (const float*)d_in[4];
    const float* Wr0 = (const float*)d_in[5];
    const float* Wl1 = (const float*)d_in[6];
    const float* bl1 = (const float*)d_in[7];
    const float* Wr1 = (const float*)d_in[8];
    const float* Wg1 = (const float*)d_in[9];
    const float* bg1 = (const float*)d_in[10];
    const float* Wg2 = (const float*)d_in[11];
    const float* Wh  = (const float*)d_in[13];
    const float* bh  = (const float*)d_in[14];
    float* out = (float*)d_out;

    const int* srcp = ei;
    const int* dstp = ei + NE;

    char* w = (char*)d_ws;
    size_t off = 0;
    auto alloc = [&](size_t bytes) { void* p = w + off; off += (bytes + 255) & ~(size_t)255; return p; };
    u32* H2    = (u32*)alloc((size_t)NN * 128 * 4);  // packed h2
    u32* H1    = (u32*)alloc((size_t)NN * 128 * 4);  // packed h1
    float* gate  = (float*)alloc((size_t)NN * 4);
    int* cnt     = (int*)alloc((size_t)NN * 4);
    int* rowp    = (int*)alloc((size_t)(NN + 1) * 4);
    int* fill    = (int*)alloc((size_t)NN * 4);
    int* cidx    = (int*)alloc((size_t)NE * 4);
    int* blksum  = (int*)alloc(128 * 4);
    int* blkoff  = (int*)alloc(128 * 4);
    float* gm    = (float*)alloc(NG * 4);
    float* gden  = (float*)alloc(NG * 4);
    float* gacc  = (float*)alloc((size_t)NG * 128 * 4);
    u16* wt      = (u16*)alloc((size_t)5 * 32768 * 2);   // 5 mats x (hi|lo) [c][k] bf16

    hipMemsetAsync(cnt, 0, (size_t)NN * 4, stream);
    hipMemsetAsync(fill, 0, (size_t)NN * 4, stream);
    hipMemsetAsync(gacc, 0, (size_t)NG * 128 * 4, stream);

    // weight transpose + bf16 hi/lo split (mat order: Wl0, Wr0, Wl1, Wr1, Wg1)
    k_cvtw<<<320, 256, 0, stream>>>(Wl0, Wr0, Wl1, Wr1, Wg1, wt);

    // CSR build (reused by both layers)
    k_hist<<<(NE + 255) / 256, 256, 0, stream>>>(dstp, cnt);
    int nb = (NN + SB - 1) / SB;
    k_scan1<<<nb, SB, 0, stream>>>(cnt, rowp, blksum);
    k_scan2<<<1, 128, 0, stream>>>(blksum, blkoff, nb);
    k_scan3<<<(NN + 1 + 255) / 256, 256, 0, stream>>>(rowp, blkoff);
    k_scatter<<<(NE + 255) / 256, 256, 0, stream>>>(srcp, dstp, rowp, fill, cidx);

    int gf = (NN + 63) / 64;             // 1563 fused blocks (64-node tiles)
    int gs = (NN + 127) / 128;           // 782 gate blocks (128-node tiles)
    u16* Wl0hi = wt;
    u16* Wl0lo = wt + 16384;
    u16* Wr0hi = wt + 32768;
    u16* Wr0lo = wt + 49152;
    u16* Wl1hi = wt + 65536;
    u16* Wl1lo = wt + 81920;
    u16* Wr1hi = wt + 98304;
    u16* Wr1lo = wt + 114688;
    u16* Wg1hi = wt + 131072;
    u16* Wg1lo = wt + 147456;
    // layer 0: X = fp32 x -> packed h1
    k_fsage<1><<<gf, 256, 0, stream>>>(x, Wl0hi, Wl0lo, bl0, Wr0hi, Wr0lo, rowp, cidx, H1);
    // layer 1: X = packed h1 -> packed h2
    k_fsage<0><<<gf, 256, 0, stream>>>(H1, Wl1hi, Wl1lo, bl1, Wr1hi, Wr1lo, rowp, cidx, H2);
    // gate + pool + head
    k_gatef_mf<<<gs, 256, 0, stream>>>(H2, Wg1hi, Wg1lo, bg1, Wg2, gate);
    k_pstats<<<NG, 256, 0, stream>>>(gate, batch, gm, gden);
    k_pacc<<<(NN + 127) / 128, 256, 0, stream>>>(H2, gate, batch, gm, gden, gacc);
    k_head<<<NG, 64, 0, stream>>>(gacc, Wh, bh, out);
}

// Round 11
// 736.716 us; speedup vs baseline: 1.5501x; 1.0543x over previous
//
#include <hip/hip_runtime.h>
#include <math.h>

#define NN 100000
#define NE 1600000
#define NG 64

typedef unsigned short u16;
typedef unsigned int u32;
typedef __attribute__((ext_vector_type(8))) short short8;   // 8 bf16 = 4 VGPR
typedef __attribute__((ext_vector_type(4))) float f32x4;    // MFMA C/D

__device__ __forceinline__ float gelu_f(float x) {
    return 0.5f * x * (1.0f + erff(x * 0.7071067811865475f));
}
// round-to-nearest-even fp32 -> bf16
__device__ __forceinline__ u16 f2bf(float f) {
    u32 u = __float_as_uint(f);
    u32 r = u + 0x7FFFu + ((u >> 16) & 1u);
    return (u16)(r >> 16);
}
__device__ __forceinline__ float bf2f(u16 h) { return __uint_as_float(((u32)h) << 16); }
// packed hi/lo bf16 pair in one u32: value ~= hi + lo, rel err ~2^-18
__device__ __forceinline__ u32 packf(float v) {
    u16 h = f2bf(v);
    u16 l = f2bf(v - bf2f(h));
    return (((u32)h) << 16) | (u32)l;
}
__device__ __forceinline__ float unpackf(u32 p) {
    return __uint_as_float(p & 0xFFFF0000u) + __uint_as_float(p << 16);
}
// 8 packed elems (2 uint4) -> hi/lo short8 for MFMA A-operand
__device__ __forceinline__ void unpack8(uint4 q0, uint4 q1, short8& hi, short8& lo) {
    u32 v[8] = {q0.x, q0.y, q0.z, q0.w, q1.x, q1.y, q1.z, q1.w};
#pragma unroll
    for (int e = 0; e < 8; ++e) {
        hi[e] = (short)(v[e] >> 16);
        lo[e] = (short)(v[e] & 0xFFFFu);
    }
}
#define MFMA __builtin_amdgcn_mfma_f32_16x16x32_bf16

// ---------------- CSR build ----------------
__global__ void k_hist(const int* __restrict__ dstp, int* __restrict__ cnt) {
    int e = blockIdx.x * 256 + threadIdx.x;
    if (e < NE) atomicAdd(&cnt[dstp[e]], 1);
}

#define SB 1024
__global__ __launch_bounds__(SB) void k_scan1(const int* __restrict__ cnt, int* __restrict__ rowp,
                                              int* __restrict__ blksum) {
    __shared__ int s[SB];
    int tid = threadIdx.x;
    int i = blockIdx.x * SB + tid;
    int v = (i < NN) ? cnt[i] : 0;
    int run = v;
    s[tid] = v;
    __syncthreads();
    for (int off = 1; off < SB; off <<= 1) {
        int t = (tid >= off) ? s[tid - off] : 0;
        __syncthreads();
        run += t;
        s[tid] = run;
        __syncthreads();
    }
    if (i < NN) rowp[i] = run - v;
    if (tid == SB - 1) blksum[blockIdx.x] = run;
}

__global__ void k_scan2(const int* __restrict__ blksum, int* __restrict__ blkoff, int nb) {
    __shared__ int s[128];
    int tid = threadIdx.x;
    int v = (tid < nb) ? blksum[tid] : 0;
    int run = v;
    s[tid] = v;
    __syncthreads();
    for (int off = 1; off < 128; off <<= 1) {
        int t = (tid >= off) ? s[tid - off] : 0;
        __syncthreads();
        run += t;
        s[tid] = run;
        __syncthreads();
    }
    if (tid < nb) blkoff[tid] = run - v;
}

__global__ void k_scan3(int* __restrict__ rowp, const int* __restrict__ blkoff) {
    int i = blockIdx.x * 256 + threadIdx.x;
    if (i < NN) rowp[i] += blkoff[i >> 10];
    else if (i == NN) rowp[NN] = NE;
}

__global__ void k_scatter(const int* __restrict__ srcp, const int* __restrict__ dstp,
                          const int* __restrict__ rowp, int* __restrict__ fill,
                          int* __restrict__ cidx) {
    int e = blockIdx.x * 256 + threadIdx.x;
    if (e < NE) {
        int d = dstp[e];
        int pos = atomicAdd(&fill[d], 1);
        cidx[rowp[d] + pos] = srcp[e];
    }
}

// ---------------- repack: fp32 row-major x -> packed slice-major XS[16][NN][8] ----------------
__global__ __launch_bounds__(256) void k_repack(const float* __restrict__ x, u32* __restrict__ XS) {
    int node = blockIdx.x * 32 + (threadIdx.x >> 3);
    int l8 = threadIdx.x & 7;
    if (node >= NN) return;
#pragma unroll
    for (int s = 0; s < 16; ++s) {
        float v = x[(size_t)node * 128 + s * 8 + l8];
        XS[((size_t)s * NN + node) * 8 + l8] = packf(v);
    }
}

// ---------------- slice-major mean-aggregate ----------------
// XS, outS are [16][NN][8] packed u32. Block = (slice s, 32 dst-nodes) x 8 lanes.
// Slice = 3.2MB contiguous -> fits one XCD's 4MB L2; slice pinned to an XCD via the
// round-robin blockIdx%8 dispatch (blocks [0,25000): s=b&7; [25000,50000): s=8+(b&7)).
// Each XCD streams its slice once, then gathers L2-hit. Correctness is mapping-
// independent (any dispatch order gives the same sums).
__global__ __launch_bounds__(256) void k_aggS(const u32* __restrict__ XS, const int* __restrict__ rowp,
                                              const int* __restrict__ cidx, u32* __restrict__ outS) {
    int b = blockIdx.x;
    int s, tile;
    if (b < 25000) { s = b & 7;                 tile = b >> 3; }
    else           { b -= 25000; s = 8 + (b & 7); tile = b >> 3; }
    int node = tile * 32 + (threadIdx.x >> 3);
    int l8 = threadIdx.x & 7;
    if (node >= NN) return;
    const u32* base = XS + (size_t)s * NN * 8 + l8;
    int beg = rowp[node], endp = rowp[node + 1];
    float sum = 0.f;
    int e = beg;
    for (; e + 7 < endp; e += 8) {
        int i0 = cidx[e],     i1 = cidx[e + 1], i2 = cidx[e + 2], i3 = cidx[e + 3];
        int i4 = cidx[e + 4], i5 = cidx[e + 5], i6 = cidx[e + 6], i7 = cidx[e + 7];
        u32 v0 = base[(size_t)i0 * 8], v1 = base[(size_t)i1 * 8];
        u32 v2 = base[(size_t)i2 * 8], v3 = base[(size_t)i3 * 8];
        u32 v4 = base[(size_t)i4 * 8], v5 = base[(size_t)i5 * 8];
        u32 v6 = base[(size_t)i6 * 8], v7 = base[(size_t)i7 * 8];
        sum += ((unpackf(v0) + unpackf(v1)) + (unpackf(v2) + unpackf(v3))) +
               ((unpackf(v4) + unpackf(v5)) + (unpackf(v6) + unpackf(v7)));
    }
    for (; e < endp; ++e) sum += unpackf(base[(size_t)cidx[e] * 8]);
    float inv = 1.0f / fmaxf((float)(endp - beg), 1.0f);
    outS[((size_t)s * NN + node) * 8 + l8] = packf(sum * inv);
}

// ---------------- weight prep: transpose + bf16 hi/lo split (planes) ----------------
__global__ __launch_bounds__(256) void k_cvtw(const float* __restrict__ W0, const float* __restrict__ W1,
                                              const float* __restrict__ W2, const float* __restrict__ W3,
                                              const float* __restrict__ W4, u16* __restrict__ dst) {
    int idx = blockIdx.x * 256 + threadIdx.x;   // 5*16384
    int m = idx >> 14;
    int r = idx & 16383;
    int k = r >> 7, c = r & 127;
    const float* W = (m == 0) ? W0 : (m == 1) ? W1 : (m == 2) ? W2 : (m == 3) ? W3 : W4;
    float v = W[k * 128 + c];
    u16 h = f2bf(v);
    u16 l = f2bf(v - bf2f(h));
    u16* base = dst + (size_t)m * 32768;
    base[c * 128 + k] = h;
    base[16384 + c * 128 + k] = l;
}

// ---------------- fused SAGE layer via bf16x3 MFMA, slice-major operands ----------------
// out = gelu(A1@W1 + b1 + A2@W2); A1, A2, out all packed slice-major [16][NN][8].
// 256 thr = 4 waves; wave = 32 nodes (2 M-tiles); block = 128 nodes.
// A-fragment for k-cols [kb*32+8lg .. +7] = slice (kb*4+lg), 32B contiguous; 16
// node-lanes -> 512B coalesced. Prefetch pipelined across kb (hides L2 latency).
// In-place safety (out may alias A1 or A2): a wave reads/writes ONLY its own 32
// node-rows; all prefetch loads complete (consumed) before epilogue stores (wave
// program order). Clamped tail reads may race but feed only unstored D-rows
// (MFMA row r of A affects only row r of D).
__global__ __launch_bounds__(256) void k_sageS(const u32* A1, const u16* __restrict__ w1hi,
                                               const u16* __restrict__ w1lo, const float* __restrict__ b1,
                                               const u32* A2, const u16* __restrict__ w2hi,
                                               const u16* __restrict__ w2lo, u32* out) {
    __shared__ u16 lds[4][128][40];
    const int t = threadIdx.x;
    const int lane = t & 63;
    const int w = t >> 6;
    const int l15 = lane & 15;
    const int lg = lane >> 4;
    const int n0 = blockIdx.x * 128 + w * 32;
    const size_t KS = (size_t)4 * NN * 8;   // u32 stride between kb-slices (4 slices)
    f32x4 acc[2][8];
#pragma unroll
    for (int ti = 0; ti < 2; ++ti)
#pragma unroll
        for (int ct = 0; ct < 8; ++ct) acc[ti][ct] = (f32x4){0.f, 0.f, 0.f, 0.f};
    int nA = n0 + l15;
    int nB = n0 + 16 + l15;
    if (nA >= NN) nA = NN - 1;
    if (nB >= NN) nB = NN - 1;
    // fragment base: slice lg, node n -> A + (lg*NN + n)*8
    const u32* b1A = A1 + ((size_t)lg * NN + nA) * 8;
    const u32* b1B = A1 + ((size_t)lg * NN + nB) * 8;
    const u32* b2A = A2 + ((size_t)lg * NN + nA) * 8;
    const u32* b2B = A2 + ((size_t)lg * NN + nB) * 8;

    uint4 p1A[2][2], p1B[2][2], p2A[2][2], p2B[2][2];
    {
        const uint4* q;
        q = (const uint4*)b1A; p1A[0][0] = q[0]; p1A[0][1] = q[1];
        q = (const uint4*)b1B; p1B[0][0] = q[0]; p1B[0][1] = q[1];
        q = (const uint4*)b2A; p2A[0][0] = q[0]; p2A[0][1] = q[1];
        q = (const uint4*)b2B; p2B[0][0] = q[0]; p2B[0][1] = q[1];
    }
#pragma unroll
    for (int kb = 0; kb < 4; ++kb) {
        const int k0 = kb * 32;
        const int cur = kb & 1, nxt = cur ^ 1;
        __syncthreads();
#pragma unroll
        for (int u = 0; u < 2; ++u) {
            int unit = t + u * 256;
            int s = unit >> 7, c = unit & 127;
            const u16* src = (s == 0) ? w1hi : (s == 1) ? w1lo : (s == 2) ? w2hi : w2lo;
            const uint4* s4 = (const uint4*)(src + (size_t)c * 128 + k0);
            uint4* d4 = (uint4*)&lds[s][c][0];
            d4[0] = s4[0]; d4[1] = s4[1]; d4[2] = s4[2]; d4[3] = s4[3];
        }
        __syncthreads();
        if (kb < 3) {
            const size_t kn = (size_t)(kb + 1) * KS;
            const uint4* q;
            q = (const uint4*)(b1A + kn); p1A[nxt][0] = q[0]; p1A[nxt][1] = q[1];
            q = (const uint4*)(b1B + kn); p1B[nxt][0] = q[0]; p1B[nxt][1] = q[1];
            q = (const uint4*)(b2A + kn); p2A[nxt][0] = q[0]; p2A[nxt][1] = q[1];
            q = (const uint4*)(b2B + kn); p2B[nxt][0] = q[0]; p2B[nxt][1] = q[1];
        }
        short8 h1A, l1A, h1B, l1B, h2A, l2A, h2B, l2B;
        unpack8(p1A[cur][0], p1A[cur][1], h1A, l1A);
        unpack8(p1B[cur][0], p1B[cur][1], h1B, l1B);
        unpack8(p2A[cur][0], p2A[cur][1], h2A, l2A);
        unpack8(p2B[cur][0], p2B[cur][1], h2B, l2B);
        const int koff = 8 * lg;
#pragma unroll
        for (int ct = 0; ct < 8; ++ct) {
            int c = ct * 16 + l15;
            short8 bh1 = *(const short8*)&lds[0][c][koff];
            short8 bl1 = *(const short8*)&lds[1][c][koff];
            short8 bh2 = *(const short8*)&lds[2][c][koff];
            short8 bl2 = *(const short8*)&lds[3][c][koff];
            acc[0][ct] = MFMA(h1A, bh1, acc[0][ct], 0, 0, 0);
            acc[0][ct] = MFMA(l1A, bh1, acc[0][ct], 0, 0, 0);
            acc[0][ct] = MFMA(h1A, bl1, acc[0][ct], 0, 0, 0);
            acc[0][ct] = MFMA(h2A, bh2, acc[0][ct], 0, 0, 0);
            acc[0][ct] = MFMA(l2A, bh2, acc[0][ct], 0, 0, 0);
            acc[0][ct] = MFMA(h2A, bl2, acc[0][ct], 0, 0, 0);
            acc[1][ct] = MFMA(h1B, bh1, acc[1][ct], 0, 0, 0);
            acc[1][ct] = MFMA(l1B, bh1, acc[1][ct], 0, 0, 0);
            acc[1][ct] = MFMA(h1B, bl1, acc[1][ct], 0, 0, 0);
            acc[1][ct] = MFMA(h2B, bh2, acc[1][ct], 0, 0, 0);
            acc[1][ct] = MFMA(l2B, bh2, acc[1][ct], 0, 0, 0);
            acc[1][ct] = MFMA(h2B, bl2, acc[1][ct], 0, 0, 0);
        }
    }
#pragma unroll
    for (int ti = 0; ti < 2; ++ti) {
#pragma unroll
        for (int ct = 0; ct < 8; ++ct) {
            int c = ct * 16 + l15;
            float bb = b1[c];
            size_t sbase = ((size_t)(c >> 3) * NN) * 8 + (c & 7);
#pragma unroll
            for (int r = 0; r < 4; ++r) {
                int node = n0 + ti * 16 + lg * 4 + r;
                if (node < NN) out[sbase + (size_t)node * 8] = packf(gelu_f(acc[ti][ct][r] + bb));
            }
        }
    }
}

// ---------------- fused gate via bf16x3 MFMA (slice-major H) ----------------
__global__ __launch_bounds__(256) void k_gateS(const u32* __restrict__ H, const u16* __restrict__ wghi,
                                               const u16* __restrict__ wglo, const float* __restrict__ bg1,
                                               const float* __restrict__ Wg2, float* __restrict__ gate) {
    __shared__ u16 lds[2][128][40];
    const int t = threadIdx.x;
    const int lane = t & 63;
    const int w = t >> 6;
    const int l15 = lane & 15;
    const int lg = lane >> 4;
    const int n0 = blockIdx.x * 128 + w * 32;
    const size_t KS = (size_t)4 * NN * 8;
    f32x4 acc[2][8];
#pragma unroll
    for (int ti = 0; ti < 2; ++ti)
#pragma unroll
        for (int ct = 0; ct < 8; ++ct) acc[ti][ct] = (f32x4){0.f, 0.f, 0.f, 0.f};
    int nA = n0 + l15;
    int nB = n0 + 16 + l15;
    if (nA >= NN) nA = NN - 1;
    if (nB >= NN) nB = NN - 1;
    const u32* bA = H + ((size_t)lg * NN + nA) * 8;
    const u32* bB = H + ((size_t)lg * NN + nB) * 8;
    uint4 pA[2][2], pB[2][2];
    {
        const uint4* q;
        q = (const uint4*)bA; pA[0][0] = q[0]; pA[0][1] = q[1];
        q = (const uint4*)bB; pB[0][0] = q[0]; pB[0][1] = q[1];
    }
#pragma unroll
    for (int kb = 0; kb < 4; ++kb) {
        const int k0 = kb * 32;
        const int cur = kb & 1, nxt = cur ^ 1;
        __syncthreads();
        {
            int s = t >> 7, c = t & 127;
            const u16* src = (s == 0) ? wghi : wglo;
            const uint4* s4 = (const uint4*)(src + (size_t)c * 128 + k0);
            uint4* d4 = (uint4*)&lds[s][c][0];
            d4[0] = s4[0]; d4[1] = s4[1]; d4[2] = s4[2]; d4[3] = s4[3];
        }
        __syncthreads();
        if (kb < 3) {
            const size_t kn = (size_t)(kb + 1) * KS;
            const uint4* q;
            q = (const uint4*)(bA + kn); pA[nxt][0] = q[0]; pA[nxt][1] = q[1];
            q = (const uint4*)(bB + kn); pB[nxt][0] = q[0]; pB[nxt][1] = q[1];
        }
        short8 hAh, hAl, hBh, hBl;
        unpack8(pA[cur][0], pA[cur][1], hAh, hAl);
        unpack8(pB[cur][0], pB[cur][1], hBh, hBl);
        const int koff = 8 * lg;
#pragma unroll
        for (int ct = 0; ct < 8; ++ct) {
            int c = ct * 16 + l15;
            short8 bh = *(const short8*)&lds[0][c][koff];
            short8 bl = *(const short8*)&lds[1][c][koff];
            acc[0][ct] = MFMA(hAh, bh, acc[0][ct], 0, 0, 0);
            acc[0][ct] = MFMA(hAl, bh, acc[0][ct], 0, 0, 0);
            acc[0][ct] = MFMA(hAh, bl, acc[0][ct], 0, 0, 0);
            acc[1][ct] = MFMA(hBh, bh, acc[1][ct], 0, 0, 0);
            acc[1][ct] = MFMA(hBl, bh, acc[1][ct], 0, 0, 0);
            acc[1][ct] = MFMA(hBh, bl, acc[1][ct], 0, 0, 0);
        }
    }
    float p[2][4];
#pragma unroll
    for (int ti = 0; ti < 2; ++ti)
#pragma unroll
        for (int r = 0; r < 4; ++r) p[ti][r] = 0.f;
#pragma unroll
    for (int ct = 0; ct < 8; ++ct) {
        int c = ct * 16 + l15;
        float bb = bg1[c];
        float gv = Wg2[c];
#pragma unroll
        for (int ti = 0; ti < 2; ++ti)
#pragma unroll
            for (int r = 0; r < 4; ++r) p[ti][r] += gelu_f(acc[ti][ct][r] + bb) * gv;
    }
#pragma unroll
    for (int m = 1; m < 16; m <<= 1) {
#pragma unroll
        for (int ti = 0; ti < 2; ++ti)
#pragma unroll
            for (int r = 0; r < 4; ++r) p[ti][r] += __shfl_xor(p[ti][r], m);
    }
    if (l15 == 0) {
#pragma unroll
        for (int ti = 0; ti < 2; ++ti)
#pragma unroll
            for (int r = 0; r < 4; ++r) {
                int node = n0 + ti * 16 + lg * 4 + r;
                if (node < NN) gate[node] = p[ti][r];
            }
    }
}

// ---------------- pooling stage 1 ----------------
__global__ __launch_bounds__(256) void k_pstats(const float* __restrict__ gate, const int* __restrict__ batch,
                                                float* __restrict__ gm, float* __restrict__ gden) {
    int g = blockIdx.x;
    int lo = 0, hi = NN;
    while (lo < hi) { int mid = (lo + hi) >> 1; if (batch[mid] < g) lo = mid + 1; else hi = mid; }
    int start = lo;
    lo = start; hi = NN;
    while (lo < hi) { int mid = (lo + hi) >> 1; if (batch[mid] < g + 1) lo = mid + 1; else hi = mid; }
    int endp = lo;

    __shared__ float red[256];
    int tid = threadIdx.x;

    float m = -1e30f;
    for (int i = start + tid; i < endp; i += 256) m = fmaxf(m, gate[i]);
    red[tid] = m;
    __syncthreads();
    for (int off = 128; off; off >>= 1) {
        if (tid < off) red[tid] = fmaxf(red[tid], red[tid + off]);
        __syncthreads();
    }
    m = red[0];
    __syncthreads();

    float s = 0.f;
    for (int i = start + tid; i < endp; i += 256) s += expf(gate[i] - m);
    red[tid] = s;
    __syncthreads();
    for (int off = 128; off; off >>= 1) {
        if (tid < off) red[tid] += red[tid + off];
        __syncthreads();
    }
    if (tid == 0) { gm[g] = m; gden[g] = red[0]; }
}

// ---------------- pooling stage 2 (slice-major H) ----------------
__global__ __launch_bounds__(256) void k_pacc(const u32* __restrict__ H, const float* __restrict__ gate,
                                              const int* __restrict__ batch, const float* __restrict__ gm,
                                              const float* __restrict__ gden, float* __restrict__ gacc) {
    int c = threadIdx.x & 127;
    int h = threadIdx.x >> 7;
    const u32* hbase = H + ((size_t)(c >> 3) * NN) * 8 + (c & 7);
    int n0 = blockIdx.x * 128;
    int nend = n0 + 128;
    if (nend > NN) nend = NN;
    int i = n0 + h;
    if (i >= nend) return;
    int cur = batch[i];
    float m = gm[cur], invd = 1.0f / gden[cur];
    float acc = 0.f;
    for (; i < nend; i += 2) {
        int gi = batch[i];
        if (gi != cur) {
            atomicAdd(&gacc[cur * 128 + c], acc * invd);
            acc = 0.f;
            cur = gi;
            m = gm[cur];
            invd = 1.0f / gden[cur];
        }
        acc = fmaf(expf(gate[i] - m), unpackf(hbase[(size_t)i * 8]), acc);
    }
    atomicAdd(&gacc[cur * 128 + c], acc * invd);
}

// ---------------- head ----------------
__global__ __launch_bounds__(64) void k_head(const float* __restrict__ gacc, const float* __restrict__ Wh,
                                             const float* __restrict__ bh, float* __restrict__ out) {
    int g = blockIdx.x;
    int l = threadIdx.x;
    float v = gacc[g * 128 + l] * Wh[l] + gacc[g * 128 + 64 + l] * Wh[64 + l];
#pragma unroll
    for (int m = 1; m < 64; m <<= 1) v += __shfl_xor(v, m);
    if (l == 0) out[g] = v + bh[0];
}

extern "C" void kernel_launch(void* const* d_in, const int* in_sizes, int n_in,
                              void* d_out, int out_size, void* d_ws, size_t ws_size,
                              hipStream_t stream) {
    (void)in_sizes; (void)n_in; (void)out_size; (void)ws_size;
    const float* x   = (const float*)d_in[0];
    const int*  ei   = (const int*)d_in[1];
    const int*  batch= (const int*)d_in[2];
    const float* Wl0 = (const float*)d_in[3];
    const float* bl0 = (const float*)d_in[4];
    const float* Wr0 = (const float*)d_in[5];
    const float* Wl1 = (const float*)d_in[6];
    const float* bl1 = (const float*)d_in[7];
    const float* Wr1 = (const float*)d_in[8];
    const float* Wg1 = (const float*)d_in[9];
    const float* bg1 = (const float*)d_in[10];
    const float* Wg2 = (const float*)d_in[11];
    const float* Wh  = (const float*)d_in[13];
    const float* bh  = (const float*)d_in[14];
    float* out = (float*)d_out;

    const int* srcp = ei;
    const int* dstp = ei + NE;

    char* w = (char*)d_ws;
    size_t off = 0;
    auto alloc = [&](size_t bytes) { void* p = w + off; off += (bytes + 255) & ~(size_t)255; return p; };
    u32* A     = (u32*)alloc((size_t)NN * 128 * 4);  // slice-major: XS0 -> h1 (in-place)
    u32* B     = (u32*)alloc((size_t)NN * 128 * 4);  // slice-major: agg -> h2 (in-place)
    float* gate  = (float*)alloc((size_t)NN * 4);
    int* cnt     = (int*)alloc((size_t)NN * 4);
    int* rowp    = (int*)alloc((size_t)(NN + 1) * 4);
    int* fill    = (int*)alloc((size_t)NN * 4);
    int* cidx    = (int*)alloc((size_t)NE * 4);
    int* blksum  = (int*)alloc(128 * 4);
    int* blkoff  = (int*)alloc(128 * 4);
    float* gm    = (float*)alloc(NG * 4);
    float* gden  = (float*)alloc(NG * 4);
    float* gacc  = (float*)alloc((size_t)NG * 128 * 4);
    u16* wt      = (u16*)alloc((size_t)5 * 32768 * 2);   // 5 mats x (hi|lo) [c][k] bf16

    hipMemsetAsync(cnt, 0, (size_t)NN * 4, stream);
    hipMemsetAsync(fill, 0, (size_t)NN * 4, stream);
    hipMemsetAsync(gacc, 0, (size_t)NG * 128 * 4, stream);

    // weight transpose + bf16 hi/lo split (mat order: Wl0, Wr0, Wl1, Wr1, Wg1)
    k_cvtw<<<320, 256, 0, stream>>>(Wl0, Wr0, Wl1, Wr1, Wg1, wt);
    // x -> packed slice-major
    k_repack<<<3125, 256, 0, stream>>>(x, A);

    // CSR build (reused by both layers)
    k_hist<<<(NE + 255) / 256, 256, 0, stream>>>(dstp, cnt);
    int nb = (NN + SB - 1) / SB;
    k_scan1<<<nb, SB, 0, stream>>>(cnt, rowp, blksum);
    k_scan2<<<1, 128, 0, stream>>>(blksum, blkoff, nb);
    k_scan3<<<(NN + 1 + 255) / 256, 256, 0, stream>>>(rowp, blkoff);
    k_scatter<<<(NE + 255) / 256, 256, 0, stream>>>(srcp, dstp, rowp, fill, cidx);

    int gs = (NN + 127) / 128;           // 782 MFMA-GEMM blocks (128-node tiles)
    u16* Wl0hi = wt;
    u16* Wl0lo = wt + 16384;
    u16* Wr0hi = wt + 32768;
    u16* Wr0lo = wt + 49152;
    u16* Wl1hi = wt + 65536;
    u16* Wl1lo = wt + 81920;
    u16* Wr1hi = wt + 98304;
    u16* Wr1lo = wt + 114688;
    u16* Wg1hi = wt + 131072;
    u16* Wg1lo = wt + 147456;
    // layer 0: gather x-slices -> B; sage(B, A) -> h1 in-place over A (wave-owned rows)
    k_aggS<<<50000, 256, 0, stream>>>(A, rowp, cidx, B);
    k_sageS<<<gs, 256, 0, stream>>>(B, Wl0hi, Wl0lo, bl0, A, Wr0hi, Wr0lo, A);
    // layer 1: gather h1-slices -> B; sage(B, A) -> h2 in-place over B (wave-owned rows)
    k_aggS<<<50000, 256, 0, stream>>>(A, rowp, cidx, B);
    k_sageS<<<gs, 256, 0, stream>>>(B, Wl1hi, Wl1lo, bl1, A, Wr1hi, Wr1lo, B);
    // gate + pool + head (H = h2 in B, slice-major)
    k_gateS<<<gs, 256, 0, stream>>>(B, Wg1hi, Wg1lo, bg1, Wg2, gate);
    k_pstats<<<NG, 256, 0, stream>>>(gate, batch, gm, gden);
    k_pacc<<<(NN + 127) / 128, 256, 0, stream>>>(B, gate, batch, gm, gden, gacc);
    k_head<<<NG, 64, 0, stream>>>(gacc, Wh, bh, out);
}

// Round 12
// 723.609 us; speedup vs baseline: 1.5782x; 1.0181x over previous
//
#include <hip/hip_runtime.h>
#include <math.h>

#define NN 100000
#define NE 1600000
#define NG 64

typedef unsigned short u16;
typedef unsigned int u32;
typedef __attribute__((ext_vector_type(8))) short short8;   // 8 bf16 = 4 VGPR
typedef __attribute__((ext_vector_type(4))) float f32x4;    // MFMA C/D

__device__ __forceinline__ float gelu_f(float x) {
    return 0.5f * x * (1.0f + erff(x * 0.7071067811865475f));
}
// round-to-nearest-even fp32 -> bf16
__device__ __forceinline__ u16 f2bf(float f) {
    u32 u = __float_as_uint(f);
    u32 r = u + 0x7FFFu + ((u >> 16) & 1u);
    return (u16)(r >> 16);
}
__device__ __forceinline__ float bf2f(u16 h) { return __uint_as_float(((u32)h) << 16); }
// packed hi/lo bf16 pair in one u32: value ~= hi + lo, rel err ~2^-18
__device__ __forceinline__ u32 packf(float v) {
    u16 h = f2bf(v);
    u16 l = f2bf(v - bf2f(h));
    return (((u32)h) << 16) | (u32)l;
}
__device__ __forceinline__ float unpackf(u32 p) {
    return __uint_as_float(p & 0xFFFF0000u) + __uint_as_float(p << 16);
}
// 8 packed elems (2 uint4) -> hi/lo short8 for MFMA A-operand
__device__ __forceinline__ void unpack8(uint4 q0, uint4 q1, short8& hi, short8& lo) {
    u32 v[8] = {q0.x, q0.y, q0.z, q0.w, q1.x, q1.y, q1.z, q1.w};
#pragma unroll
    for (int e = 0; e < 8; ++e) {
        hi[e] = (short)(v[e] >> 16);
        lo[e] = (short)(v[e] & 0xFFFFu);
    }
}
#define MFMA __builtin_amdgcn_mfma_f32_16x16x32_bf16

// ---------------- CSR build ----------------
__global__ void k_hist(const int* __restrict__ dstp, int* __restrict__ cnt) {
    int e = blockIdx.x * 256 + threadIdx.x;
    if (e < NE) atomicAdd(&cnt[dstp[e]], 1);
}

#define SB 1024
__global__ __launch_bounds__(SB) void k_scan1(const int* __restrict__ cnt, int* __restrict__ rowp,
                                              int* __restrict__ blksum) {
    __shared__ int s[SB];
    int tid = threadIdx.x;
    int i = blockIdx.x * SB + tid;
    int v = (i < NN) ? cnt[i] : 0;
    int run = v;
    s[tid] = v;
    __syncthreads();
    for (int off = 1; off < SB; off <<= 1) {
        int t = (tid >= off) ? s[tid - off] : 0;
        __syncthreads();
        run += t;
        s[tid] = run;
        __syncthreads();
    }
    if (i < NN) rowp[i] = run - v;
    if (tid == SB - 1) blksum[blockIdx.x] = run;
}

__global__ void k_scan2(const int* __restrict__ blksum, int* __restrict__ blkoff, int nb) {
    __shared__ int s[128];
    int tid = threadIdx.x;
    int v = (tid < nb) ? blksum[tid] : 0;
    int run = v;
    s[tid] = v;
    __syncthreads();
    for (int off = 1; off < 128; off <<= 1) {
        int t = (tid >= off) ? s[tid - off] : 0;
        __syncthreads();
        run += t;
        s[tid] = run;
        __syncthreads();
    }
    if (tid < nb) blkoff[tid] = run - v;
}

__global__ void k_scan3(int* __restrict__ rowp, const int* __restrict__ blkoff) {
    int i = blockIdx.x * 256 + threadIdx.x;
    if (i < NN) rowp[i] += blkoff[i >> 10];
    else if (i == NN) rowp[NN] = NE;
}

__global__ void k_scatter(const int* __restrict__ srcp, const int* __restrict__ dstp,
                          const int* __restrict__ rowp, int* __restrict__ fill,
                          int* __restrict__ cidx) {
    int e = blockIdx.x * 256 + threadIdx.x;
    if (e < NE) {
        int d = dstp[e];
        int pos = atomicAdd(&fill[d], 1);
        cidx[rowp[d] + pos] = srcp[e];
    }
}

// ---------------- repack: fp32 row-major x -> packed slice-major XS[16][NN][8] ----------------
__global__ __launch_bounds__(256) void k_repack(const float* __restrict__ x, u32* __restrict__ XS) {
    int node = blockIdx.x * 32 + (threadIdx.x >> 3);
    int l8 = threadIdx.x & 7;
    if (node >= NN) return;
#pragma unroll
    for (int s = 0; s < 16; ++s) {
        float v = x[(size_t)node * 128 + s * 8 + l8];
        XS[((size_t)s * NN + node) * 8 + l8] = packf(v);
    }
}

// ---------------- slice-major mean-aggregate, wide loads ----------------
// XS, outS are [16][NN][8] packed u32. A node's slice-row is 32B contiguous ->
// gathered as 2 lanes x uint4 (16B). Block = 128 nodes x 2 lanes.
// Grid = 16 slices x 782 tiles; slice pinned to an XCD via round-robin b&7
// (blocks [0,6256): s=b&7; [6256,12512): s=8+(b&7)). Slice = 3.2MB fits one
// XCD's 4MB L2: stream once, then gather L2-hit (r11: FETCH 377->102MB).
// r11's 8x4B lanes were issue-bound (VALUBusy 49%); uint4 restores r8's
// wave-load count. Correctness is dispatch-mapping-independent.
__global__ __launch_bounds__(256) void k_aggS(const u32* __restrict__ XS, const int* __restrict__ rowp,
                                              const int* __restrict__ cidx, u32* __restrict__ outS) {
    int b = blockIdx.x;
    int s, tile;
    if (b < 6256) { s = b & 7;                 tile = b >> 3; }
    else          { b -= 6256; s = 8 + (b & 7); tile = b >> 3; }
    int node = tile * 128 + (threadIdx.x >> 1);
    int h = threadIdx.x & 1;
    if (node >= NN) return;
    const uint4* base = (const uint4*)(XS + (size_t)s * NN * 8) + h;   // elem idx: n*2 + h
    int beg = rowp[node], endp = rowp[node + 1];
    float s0 = 0.f, s1 = 0.f, s2 = 0.f, s3 = 0.f;
    int e = beg;
    for (; e + 7 < endp; e += 8) {
        int i0 = cidx[e],     i1 = cidx[e + 1], i2 = cidx[e + 2], i3 = cidx[e + 3];
        int i4 = cidx[e + 4], i5 = cidx[e + 5], i6 = cidx[e + 6], i7 = cidx[e + 7];
        uint4 v0 = base[(size_t)i0 * 2];
        uint4 v1 = base[(size_t)i1 * 2];
        uint4 v2 = base[(size_t)i2 * 2];
        uint4 v3 = base[(size_t)i3 * 2];
        uint4 v4 = base[(size_t)i4 * 2];
        uint4 v5 = base[(size_t)i5 * 2];
        uint4 v6 = base[(size_t)i6 * 2];
        uint4 v7 = base[(size_t)i7 * 2];
        s0 += ((unpackf(v0.x) + unpackf(v1.x)) + (unpackf(v2.x) + unpackf(v3.x))) +
              ((unpackf(v4.x) + unpackf(v5.x)) + (unpackf(v6.x) + unpackf(v7.x)));
        s1 += ((unpackf(v0.y) + unpackf(v1.y)) + (unpackf(v2.y) + unpackf(v3.y))) +
              ((unpackf(v4.y) + unpackf(v5.y)) + (unpackf(v6.y) + unpackf(v7.y)));
        s2 += ((unpackf(v0.z) + unpackf(v1.z)) + (unpackf(v2.z) + unpackf(v3.z))) +
              ((unpackf(v4.z) + unpackf(v5.z)) + (unpackf(v6.z) + unpackf(v7.z)));
        s3 += ((unpackf(v0.w) + unpackf(v1.w)) + (unpackf(v2.w) + unpackf(v3.w))) +
              ((unpackf(v4.w) + unpackf(v5.w)) + (unpackf(v6.w) + unpackf(v7.w)));
    }
    for (; e < endp; ++e) {
        uint4 v = base[(size_t)cidx[e] * 2];
        s0 += unpackf(v.x); s1 += unpackf(v.y); s2 += unpackf(v.z); s3 += unpackf(v.w);
    }
    float inv = 1.0f / fmaxf((float)(endp - beg), 1.0f);
    uint4 o;
    o.x = packf(s0 * inv); o.y = packf(s1 * inv); o.z = packf(s2 * inv); o.w = packf(s3 * inv);
    ((uint4*)(outS + (size_t)s * NN * 8))[(size_t)node * 2 + h] = o;
}

// ---------------- weight prep: transpose + bf16 hi/lo split (planes) ----------------
__global__ __launch_bounds__(256) void k_cvtw(const float* __restrict__ W0, const float* __restrict__ W1,
                                              const float* __restrict__ W2, const float* __restrict__ W3,
                                              const float* __restrict__ W4, u16* __restrict__ dst) {
    int idx = blockIdx.x * 256 + threadIdx.x;   // 5*16384
    int m = idx >> 14;
    int r = idx & 16383;
    int k = r >> 7, c = r & 127;
    const float* W = (m == 0) ? W0 : (m == 1) ? W1 : (m == 2) ? W2 : (m == 3) ? W3 : W4;
    float v = W[k * 128 + c];
    u16 h = f2bf(v);
    u16 l = f2bf(v - bf2f(h));
    u16* base = dst + (size_t)m * 32768;
    base[c * 128 + k] = h;
    base[16384 + c * 128 + k] = l;
}

// ---------------- fused SAGE layer via bf16x3 MFMA, slice-major operands ----------------
// out = gelu(A1@W1 + b1 + A2@W2); A1, A2, out all packed slice-major [16][NN][8].
// 256 thr = 4 waves; wave = 32 nodes (2 M-tiles); block = 128 nodes.
// In-place safety (out may alias A1 or A2): a wave reads/writes ONLY its own 32
// node-rows; prefetch loads are consumed before epilogue stores (wave program
// order). Clamped tail reads feed only unstored D-rows.
__global__ __launch_bounds__(256) void k_sageS(const u32* A1, const u16* __restrict__ w1hi,
                                               const u16* __restrict__ w1lo, const float* __restrict__ b1,
                                               const u32* A2, const u16* __restrict__ w2hi,
                                               const u16* __restrict__ w2lo, u32* out) {
    __shared__ u16 lds[4][128][40];
    const int t = threadIdx.x;
    const int lane = t & 63;
    const int w = t >> 6;
    const int l15 = lane & 15;
    const int lg = lane >> 4;
    const int n0 = blockIdx.x * 128 + w * 32;
    const size_t KS = (size_t)4 * NN * 8;   // u32 stride between kb-slices (4 slices)
    f32x4 acc[2][8];
#pragma unroll
    for (int ti = 0; ti < 2; ++ti)
#pragma unroll
        for (int ct = 0; ct < 8; ++ct) acc[ti][ct] = (f32x4){0.f, 0.f, 0.f, 0.f};
    int nA = n0 + l15;
    int nB = n0 + 16 + l15;
    if (nA >= NN) nA = NN - 1;
    if (nB >= NN) nB = NN - 1;
    const u32* b1A = A1 + ((size_t)lg * NN + nA) * 8;
    const u32* b1B = A1 + ((size_t)lg * NN + nB) * 8;
    const u32* b2A = A2 + ((size_t)lg * NN + nA) * 8;
    const u32* b2B = A2 + ((size_t)lg * NN + nB) * 8;

    uint4 p1A[2][2], p1B[2][2], p2A[2][2], p2B[2][2];
    {
        const uint4* q;
        q = (const uint4*)b1A; p1A[0][0] = q[0]; p1A[0][1] = q[1];
        q = (const uint4*)b1B; p1B[0][0] = q[0]; p1B[0][1] = q[1];
        q = (const uint4*)b2A; p2A[0][0] = q[0]; p2A[0][1] = q[1];
        q = (const uint4*)b2B; p2B[0][0] = q[0]; p2B[0][1] = q[1];
    }
#pragma unroll
    for (int kb = 0; kb < 4; ++kb) {
        const int k0 = kb * 32;
        const int cur = kb & 1, nxt = cur ^ 1;
        __syncthreads();
#pragma unroll
        for (int u = 0; u < 2; ++u) {
            int unit = t + u * 256;
            int s = unit >> 7, c = unit & 127;
            const u16* src = (s == 0) ? w1hi : (s == 1) ? w1lo : (s == 2) ? w2hi : w2lo;
            const uint4* s4 = (const uint4*)(src + (size_t)c * 128 + k0);
            uint4* d4 = (uint4*)&lds[s][c][0];
            d4[0] = s4[0]; d4[1] = s4[1]; d4[2] = s4[2]; d4[3] = s4[3];
        }
        __syncthreads();
        if (kb < 3) {
            const size_t kn = (size_t)(kb + 1) * KS;
            const uint4* q;
            q = (const uint4*)(b1A + kn); p1A[nxt][0] = q[0]; p1A[nxt][1] = q[1];
            q = (const uint4*)(b1B + kn); p1B[nxt][0] = q[0]; p1B[nxt][1] = q[1];
            q = (const uint4*)(b2A + kn); p2A[nxt][0] = q[0]; p2A[nxt][1] = q[1];
            q = (const uint4*)(b2B + kn); p2B[nxt][0] = q[0]; p2B[nxt][1] = q[1];
        }
        short8 h1A, l1A, h1B, l1B, h2A, l2A, h2B, l2B;
        unpack8(p1A[cur][0], p1A[cur][1], h1A, l1A);
        unpack8(p1B[cur][0], p1B[cur][1], h1B, l1B);
        unpack8(p2A[cur][0], p2A[cur][1], h2A, l2A);
        unpack8(p2B[cur][0], p2B[cur][1], h2B, l2B);
        const int koff = 8 * lg;
#pragma unroll
        for (int ct = 0; ct < 8; ++ct) {
            int c = ct * 16 + l15;
            short8 bh1 = *(const short8*)&lds[0][c][koff];
            short8 bl1 = *(const short8*)&lds[1][c][koff];
            short8 bh2 = *(const short8*)&lds[2][c][koff];
            short8 bl2 = *(const short8*)&lds[3][c][koff];
            acc[0][ct] = MFMA(h1A, bh1, acc[0][ct], 0, 0, 0);
            acc[0][ct] = MFMA(l1A, bh1, acc[0][ct], 0, 0, 0);
            acc[0][ct] = MFMA(h1A, bl1, acc[0][ct], 0, 0, 0);
            acc[0][ct] = MFMA(h2A, bh2, acc[0][ct], 0, 0, 0);
            acc[0][ct] = MFMA(l2A, bh2, acc[0][ct], 0, 0, 0);
            acc[0][ct] = MFMA(h2A, bl2, acc[0][ct], 0, 0, 0);
            acc[1][ct] = MFMA(h1B, bh1, acc[1][ct], 0, 0, 0);
            acc[1][ct] = MFMA(l1B, bh1, acc[1][ct], 0, 0, 0);
            acc[1][ct] = MFMA(h1B, bl1, acc[1][ct], 0, 0, 0);
            acc[1][ct] = MFMA(h2B, bh2, acc[1][ct], 0, 0, 0);
            acc[1][ct] = MFMA(l2B, bh2, acc[1][ct], 0, 0, 0);
            acc[1][ct] = MFMA(h2B, bl2, acc[1][ct], 0, 0, 0);
        }
    }
#pragma unroll
    for (int ti = 0; ti < 2; ++ti) {
#pragma unroll
        for (int ct = 0; ct < 8; ++ct) {
            int c = ct * 16 + l15;
            float bb = b1[c];
            size_t sbase = ((size_t)(c >> 3) * NN) * 8 + (c & 7);
#pragma unroll
            for (int r = 0; r < 4; ++r) {
                int node = n0 + ti * 16 + lg * 4 + r;
                if (node < NN) out[sbase + (size_t)node * 8] = packf(gelu_f(acc[ti][ct][r] + bb));
            }
        }
    }
}

// ---------------- fused gate via bf16x3 MFMA (slice-major H) ----------------
__global__ __launch_bounds__(256) void k_gateS(const u32* __restrict__ H, const u16* __restrict__ wghi,
                                               const u16* __restrict__ wglo, const float* __restrict__ bg1,
                                               const float* __restrict__ Wg2, float* __restrict__ gate) {
    __shared__ u16 lds[2][128][40];
    const int t = threadIdx.x;
    const int lane = t & 63;
    const int w = t >> 6;
    const int l15 = lane & 15;
    const int lg = lane >> 4;
    const int n0 = blockIdx.x * 128 + w * 32;
    const size_t KS = (size_t)4 * NN * 8;
    f32x4 acc[2][8];
#pragma unroll
    for (int ti = 0; ti < 2; ++ti)
#pragma unroll
        for (int ct = 0; ct < 8; ++ct) acc[ti][ct] = (f32x4){0.f, 0.f, 0.f, 0.f};
    int nA = n0 + l15;
    int nB = n0 + 16 + l15;
    if (nA >= NN) nA = NN - 1;
    if (nB >= NN) nB = NN - 1;
    const u32* bA = H + ((size_t)lg * NN + nA) * 8;
    const u32* bB = H + ((size_t)lg * NN + nB) * 8;
    uint4 pA[2][2], pB[2][2];
    {
        const uint4* q;
        q = (const uint4*)bA; pA[0][0] = q[0]; pA[0][1] = q[1];
        q = (const uint4*)bB; pB[0][0] = q[0]; pB[0][1] = q[1];
    }
#pragma unroll
    for (int kb = 0; kb < 4; ++kb) {
        const int k0 = kb * 32;
        const int cur = kb & 1, nxt = cur ^ 1;
        __syncthreads();
        {
            int s = t >> 7, c = t & 127;
            const u16* src = (s == 0) ? wghi : wglo;
            const uint4* s4 = (const uint4*)(src + (size_t)c * 128 + k0);
            uint4* d4 = (uint4*)&lds[s][c][0];
            d4[0] = s4[0]; d4[1] = s4[1]; d4[2] = s4[2]; d4[3] = s4[3];
        }
        __syncthreads();
        if (kb < 3) {
            const size_t kn = (size_t)(kb + 1) * KS;
            const uint4* q;
            q = (const uint4*)(bA + kn); pA[nxt][0] = q[0]; pA[nxt][1] = q[1];
            q = (const uint4*)(bB + kn); pB[nxt][0] = q[0]; pB[nxt][1] = q[1];
        }
        short8 hAh, hAl, hBh, hBl;
        unpack8(pA[cur][0], pA[cur][1], hAh, hAl);
        unpack8(pB[cur][0], pB[cur][1], hBh, hBl);
        const int koff = 8 * lg;
#pragma unroll
        for (int ct = 0; ct < 8; ++ct) {
            int c = ct * 16 + l15;
            short8 bh = *(const short8*)&lds[0][c][koff];
            short8 bl = *(const short8*)&lds[1][c][koff];
            acc[0][ct] = MFMA(hAh, bh, acc[0][ct], 0, 0, 0);
            acc[0][ct] = MFMA(hAl, bh, acc[0][ct], 0, 0, 0);
            acc[0][ct] = MFMA(hAh, bl, acc[0][ct], 0, 0, 0);
            acc[1][ct] = MFMA(hBh, bh, acc[1][ct], 0, 0, 0);
            acc[1][ct] = MFMA(hBl, bh, acc[1][ct], 0, 0, 0);
            acc[1][ct] = MFMA(hBh, bl, acc[1][ct], 0, 0, 0);
        }
    }
    float p[2][4];
#pragma unroll
    for (int ti = 0; ti < 2; ++ti)
#pragma unroll
        for (int r = 0; r < 4; ++r) p[ti][r] = 0.f;
#pragma unroll
    for (int ct = 0; ct < 8; ++ct) {
        int c = ct * 16 + l15;
        float bb = bg1[c];
        float gv = Wg2[c];
#pragma unroll
        for (int ti = 0; ti < 2; ++ti)
#pragma unroll
            for (int r = 0; r < 4; ++r) p[ti][r] += gelu_f(acc[ti][ct][r] + bb) * gv;
    }
#pragma unroll
    for (int m = 1; m < 16; m <<= 1) {
#pragma unroll
        for (int ti = 0; ti < 2; ++ti)
#pragma unroll
            for (int r = 0; r < 4; ++r) p[ti][r] += __shfl_xor(p[ti][r], m);
    }
    if (l15 == 0) {
#pragma unroll
        for (int ti = 0; ti < 2; ++ti)
#pragma unroll
            for (int r = 0; r < 4; ++r) {
                int node = n0 + ti * 16 + lg * 4 + r;
                if (node < NN) gate[node] = p[ti][r];
            }
    }
}

// ---------------- pooling stage 1 ----------------
__global__ __launch_bounds__(256) void k_pstats(const float* __restrict__ gate, const int* __restrict__ batch,
                                                float* __restrict__ gm, float* __restrict__ gden) {
    int g = blockIdx.x;
    int lo = 0, hi = NN;
    while (lo < hi) { int mid = (lo + hi) >> 1; if (batch[mid] < g) lo = mid + 1; else hi = mid; }
    int start = lo;
    lo = start; hi = NN;
    while (lo < hi) { int mid = (lo + hi) >> 1; if (batch[mid] < g + 1) lo = mid + 1; else hi = mid; }
    int endp = lo;

    __shared__ float red[256];
    int tid = threadIdx.x;

    float m = -1e30f;
    for (int i = start + tid; i < endp; i += 256) m = fmaxf(m, gate[i]);
    red[tid] = m;
    __syncthreads();
    for (int off = 128; off; off >>= 1) {
        if (tid < off) red[tid] = fmaxf(red[tid], red[tid + off]);
        __syncthreads();
    }
    m = red[0];
    __syncthreads();

    float s = 0.f;
    for (int i = start + tid; i < endp; i += 256) s += expf(gate[i] - m);
    red[tid] = s;
    __syncthreads();
    for (int off = 128; off; off >>= 1) {
        if (tid < off) red[tid] += red[tid + off];
        __syncthreads();
    }
    if (tid == 0) { gm[g] = m; gden[g] = red[0]; }
}

// ---------------- pooling stage 2 (slice-major H) ----------------
__global__ __launch_bounds__(256) void k_pacc(const u32* __restrict__ H, const float* __restrict__ gate,
                                              const int* __restrict__ batch, const float* __restrict__ gm,
                                              const float* __restrict__ gden, float* __restrict__ gacc) {
    int c = threadIdx.x & 127;
    int h = threadIdx.x >> 7;
    const u32* hbase = H + ((size_t)(c >> 3) * NN) * 8 + (c & 7);
    int n0 = blockIdx.x * 128;
    int nend = n0 + 128;
    if (nend > NN) nend = NN;
    int i = n0 + h;
    if (i >= nend) return;
    int cur = batch[i];
    float m = gm[cur], invd = 1.0f / gden[cur];
    float acc = 0.f;
    for (; i < nend; i += 2) {
        int gi = batch[i];
        if (gi != cur) {
            atomicAdd(&gacc[cur * 128 + c], acc * invd);
            acc = 0.f;
            cur = gi;
            m = gm[cur];
            invd = 1.0f / gden[cur];
        }
        acc = fmaf(expf(gate[i] - m), unpackf(hbase[(size_t)i * 8]), acc);
    }
    atomicAdd(&gacc[cur * 128 + c], acc * invd);
}

// ---------------- head ----------------
__global__ __launch_bounds__(64) void k_head(const float* __restrict__ gacc, const float* __restrict__ Wh,
                                             const float* __restrict__ bh, float* __restrict__ out) {
    int g = blockIdx.x;
    int l = threadIdx.x;
    float v = gacc[g * 128 + l] * Wh[l] + gacc[g * 128 + 64 + l] * Wh[64 + l];
#pragma unroll
    for (int m = 1; m < 64; m <<= 1) v += __shfl_xor(v, m);
    if (l == 0) out[g] = v + bh[0];
}

extern "C" void kernel_launch(void* const* d_in, const int* in_sizes, int n_in,
                              void* d_out, int out_size, void* d_ws, size_t ws_size,
                              hipStream_t stream) {
    (void)in_sizes; (void)n_in; (void)out_size; (void)ws_size;
    const float* x   = (const float*)d_in[0];
    const int*  ei   = (const int*)d_in[1];
    const int*  batch= (const int*)d_in[2];
    const float* Wl0 = (const float*)d_in[3];
    const float* bl0 = (const float*)d_in[4];
    const float* Wr0 = (const float*)d_in[5];
    const float* Wl1 = (const float*)d_in[6];
    const float* bl1 = (const float*)d_in[7];
    const float* Wr1 = (const float*)d_in[8];
    const float* Wg1 = (const float*)d_in[9];
    const float* bg1 = (const float*)d_in[10];
    const float* Wg2 = (const float*)d_in[11];
    const float* Wh  = (const float*)d_in[13];
    const float* bh  = (const float*)d_in[14];
    float* out = (float*)d_out;

    const int* srcp = ei;
    const int* dstp = ei + NE;

    char* w = (char*)d_ws;
    size_t off = 0;
    auto alloc = [&](size_t bytes) { void* p = w + off; off += (bytes + 255) & ~(size_t)255; return p; };
    u32* A     = (u32*)alloc((size_t)NN * 128 * 4);  // slice-major: XS0 -> h1 (in-place)
    u32* B     = (u32*)alloc((size_t)NN * 128 * 4);  // slice-major: agg -> h2 (in-place)
    float* gate  = (float*)alloc((size_t)NN * 4);
    int* cnt     = (int*)alloc((size_t)NN * 4);
    int* rowp    = (int*)alloc((size_t)(NN + 1) * 4);
    int* fill    = (int*)alloc((size_t)NN * 4);
    int* cidx    = (int*)alloc((size_t)NE * 4);
    int* blksum  = (int*)alloc(128 * 4);
    int* blkoff  = (int*)alloc(128 * 4);
    float* gm    = (float*)alloc(NG * 4);
    float* gden  = (float*)alloc(NG * 4);
    float* gacc  = (float*)alloc((size_t)NG * 128 * 4);
    u16* wt      = (u16*)alloc((size_t)5 * 32768 * 2);   // 5 mats x (hi|lo) [c][k] bf16

    hipMemsetAsync(cnt, 0, (size_t)NN * 4, stream);
    hipMemsetAsync(fill, 0, (size_t)NN * 4, stream);
    hipMemsetAsync(gacc, 0, (size_t)NG * 128 * 4, stream);

    // weight transpose + bf16 hi/lo split (mat order: Wl0, Wr0, Wl1, Wr1, Wg1)
    k_cvtw<<<320, 256, 0, stream>>>(Wl0, Wr0, Wl1, Wr1, Wg1, wt);
    // x -> packed slice-major
    k_repack<<<3125, 256, 0, stream>>>(x, A);

    // CSR build (reused by both layers)
    k_hist<<<(NE + 255) / 256, 256, 0, stream>>>(dstp, cnt);
    int nb = (NN + SB - 1) / SB;
    k_scan1<<<nb, SB, 0, stream>>>(cnt, rowp, blksum);
    k_scan2<<<1, 128, 0, stream>>>(blksum, blkoff, nb);
    k_scan3<<<(NN + 1 + 255) / 256, 256, 0, stream>>>(rowp, blkoff);
    k_scatter<<<(NE + 255) / 256, 256, 0, stream>>>(srcp, dstp, rowp, fill, cidx);

    int gs = (NN + 127) / 128;           // 782 MFMA-GEMM blocks (128-node tiles)
    int ga = 2 * 8 * gs;                 // 16 slices x 782 tiles = 12512
    u16* Wl0hi = wt;
    u16* Wl0lo = wt + 16384;
    u16* Wr0hi = wt + 32768;
    u16* Wr0lo = wt + 49152;
    u16* Wl1hi = wt + 65536;
    u16* Wl1lo = wt + 81920;
    u16* Wr1hi = wt + 98304;
    u16* Wr1lo = wt + 114688;
    u16* Wg1hi = wt + 131072;
    u16* Wg1lo = wt + 147456;
    // layer 0: gather x-slices -> B; sage(B, A) -> h1 in-place over A (wave-owned rows)
    k_aggS<<<ga, 256, 0, stream>>>(A, rowp, cidx, B);
    k_sageS<<<gs, 256, 0, stream>>>(B, Wl0hi, Wl0lo, bl0, A, Wr0hi, Wr0lo, A);
    // layer 1: gather h1-slices -> B; sage(B, A) -> h2 in-place over B (wave-owned rows)
    k_aggS<<<ga, 256, 0, stream>>>(A, rowp, cidx, B);
    k_sageS<<<gs, 256, 0, stream>>>(B, Wl1hi, Wl1lo, bl1, A, Wr1hi, Wr1lo, B);
    // gate + pool + head (H = h2 in B, slice-major)
    k_gateS<<<gs, 256, 0, stream>>>(B, Wg1hi, Wg1lo, bg1, Wg2, gate);
    k_pstats<<<NG, 256, 0, stream>>>(gate, batch, gm, gden);
    k_pacc<<<(NN + 127) / 128, 256, 0, stream>>>(B, gate, batch, gm, gden, gacc);
    k_head<<<NG, 64, 0, stream>>>(gacc, Wh, bh, out);
}

// Round 13
// 592.381 us; speedup vs baseline: 1.9278x; 1.2215x over previous
//
#include <hip/hip_runtime.h>
#include <math.h>

#define NN 100000
#define NE 1600000
#define NG 64

typedef unsigned short u16;
typedef unsigned int u32;
typedef __attribute__((ext_vector_type(8))) short short8;   // 8 bf16 = 4 VGPR
typedef __attribute__((ext_vector_type(4))) float f32x4;    // MFMA C/D

__device__ __forceinline__ float gelu_f(float x) {
    return 0.5f * x * (1.0f + erff(x * 0.7071067811865475f));
}
// round-to-nearest-even fp32 -> bf16
__device__ __forceinline__ u16 f2bf(float f) {
    u32 u = __float_as_uint(f);
    u32 r = u + 0x7FFFu + ((u >> 16) & 1u);
    return (u16)(r >> 16);
}
__device__ __forceinline__ float bf2f(u16 h) { return __uint_as_float(((u32)h) << 16); }
// packed hi/lo bf16 pair in one u32: value ~= hi + lo, rel err ~2^-18
__device__ __forceinline__ u32 packf(float v) {
    u16 h = f2bf(v);
    u16 l = f2bf(v - bf2f(h));
    return (((u32)h) << 16) | (u32)l;
}
__device__ __forceinline__ float unpackf(u32 p) {
    return __uint_as_float(p & 0xFFFF0000u) + __uint_as_float(p << 16);
}
// 8 packed elems (2 uint4) -> hi/lo short8 for MFMA A-operand
__device__ __forceinline__ void unpack8(uint4 q0, uint4 q1, short8& hi, short8& lo) {
    u32 v[8] = {q0.x, q0.y, q0.z, q0.w, q1.x, q1.y, q1.z, q1.w};
#pragma unroll
    for (int e = 0; e < 8; ++e) {
        hi[e] = (short)(v[e] >> 16);
        lo[e] = (short)(v[e] & 0xFFFFu);
    }
}
// 8 fp32 elems (2 float4) -> hi/lo short8
__device__ __forceinline__ void cvt8f(float4 f0, float4 f1, short8& hi, short8& lo) {
    float v[8] = {f0.x, f0.y, f0.z, f0.w, f1.x, f1.y, f1.z, f1.w};
#pragma unroll
    for (int e = 0; e < 8; ++e) {
        u16 h = f2bf(v[e]);
        hi[e] = (short)h;
        lo[e] = (short)f2bf(v[e] - bf2f(h));
    }
}
#define MFMA __builtin_amdgcn_mfma_f32_16x16x32_bf16

// ---------------- CSR build ----------------
__global__ void k_hist(const int* __restrict__ dstp, int* __restrict__ cnt) {
    int e = blockIdx.x * 256 + threadIdx.x;
    if (e < NE) atomicAdd(&cnt[dstp[e]], 1);
}

#define SB 1024
__global__ __launch_bounds__(SB) void k_scan1(const int* __restrict__ cnt, int* __restrict__ rowp,
                                              int* __restrict__ blksum) {
    __shared__ int s[SB];
    int tid = threadIdx.x;
    int i = blockIdx.x * SB + tid;
    int v = (i < NN) ? cnt[i] : 0;
    int run = v;
    s[tid] = v;
    __syncthreads();
    for (int off = 1; off < SB; off <<= 1) {
        int t = (tid >= off) ? s[tid - off] : 0;
        __syncthreads();
        run += t;
        s[tid] = run;
        __syncthreads();
    }
    if (i < NN) rowp[i] = run - v;
    if (tid == SB - 1) blksum[blockIdx.x] = run;
}

__global__ void k_scan2(const int* __restrict__ blksum, int* __restrict__ blkoff, int nb) {
    __shared__ int s[128];
    int tid = threadIdx.x;
    int v = (tid < nb) ? blksum[tid] : 0;
    int run = v;
    s[tid] = v;
    __syncthreads();
    for (int off = 1; off < 128; off <<= 1) {
        int t = (tid >= off) ? s[tid - off] : 0;
        __syncthreads();
        run += t;
        s[tid] = run;
        __syncthreads();
    }
    if (tid < nb) blkoff[tid] = run - v;
}

__global__ void k_scan3(int* __restrict__ rowp, const int* __restrict__ blkoff) {
    int i = blockIdx.x * 256 + threadIdx.x;
    if (i < NN) rowp[i] += blkoff[i >> 10];
    else if (i == NN) rowp[NN] = NE;
}

__global__ void k_scatter(const int* __restrict__ srcp, const int* __restrict__ dstp,
                          const int* __restrict__ rowp, int* __restrict__ fill,
                          int* __restrict__ cidx) {
    int e = blockIdx.x * 256 + threadIdx.x;
    if (e < NE) {
        int d = dstp[e];
        int pos = atomicAdd(&fill[d], 1);
        cidx[rowp[d] + pos] = srcp[e];
    }
}

// ---------------- mean-aggregate: 32 lanes x 16B per node, 8 edges in flight ----------------
// PACKED=0: src rows are fp32 (x). PACKED=1: src rows hi/lo-packed u32.
// Output packed u32 (GEMM-A-ready). r8-proven config: 118us, fabric-bound 3.7TB/s.
template <int PACKED>
__global__ __launch_bounds__(256) void k_agg(const void* __restrict__ xin, const int* __restrict__ rowp,
                                             const int* __restrict__ cidx, u32* __restrict__ agg) {
    int tid = blockIdx.x * 256 + threadIdx.x;
    int node = tid >> 5;
    int lane = tid & 31;
    if (node >= NN) return;
    int beg = rowp[node], endp = rowp[node + 1];
    const float4* xf = (const float4*)xin;
    const uint4* xp = (const uint4*)xin;
    float sx = 0.f, sy = 0.f, sz = 0.f, sw = 0.f;
    int e = beg;
    for (; e + 7 < endp; e += 8) {
        int idx[8];
#pragma unroll
        for (int u = 0; u < 8; ++u) idx[u] = cidx[e + u];
        if (PACKED) {
            uint4 q[8];
#pragma unroll
            for (int u = 0; u < 8; ++u) q[u] = xp[(size_t)idx[u] * 32 + lane];
#pragma unroll
            for (int u = 0; u < 8; ++u) {
                sx += unpackf(q[u].x); sy += unpackf(q[u].y);
                sz += unpackf(q[u].z); sw += unpackf(q[u].w);
            }
        } else {
            float4 v[8];
#pragma unroll
            for (int u = 0; u < 8; ++u) v[u] = xf[(size_t)idx[u] * 32 + lane];
#pragma unroll
            for (int u = 0; u < 8; ++u) {
                sx += v[u].x; sy += v[u].y; sz += v[u].z; sw += v[u].w;
            }
        }
    }
    for (; e < endp; ++e) {
        int i0 = cidx[e];
        if (PACKED) {
            uint4 q = xp[(size_t)i0 * 32 + lane];
            sx += unpackf(q.x); sy += unpackf(q.y); sz += unpackf(q.z); sw += unpackf(q.w);
        } else {
            float4 v = xf[(size_t)i0 * 32 + lane];
            sx += v.x; sy += v.y; sz += v.z; sw += v.w;
        }
    }
    float inv = 1.0f / fmaxf((float)(endp - beg), 1.0f);
    uint4 o;
    o.x = packf(sx * inv); o.y = packf(sy * inv); o.z = packf(sz * inv); o.w = packf(sw * inv);
    ((uint4*)agg)[(size_t)node * 32 + lane] = o;
}

// ---------------- weight prep: transpose + bf16 hi/lo split (planes) ----------------
__global__ __launch_bounds__(256) void k_cvtw(const float* __restrict__ W0, const float* __restrict__ W1,
                                              const float* __restrict__ W2, const float* __restrict__ W3,
                                              const float* __restrict__ W4, u16* __restrict__ dst) {
    int idx = blockIdx.x * 256 + threadIdx.x;   // 5*16384
    int m = idx >> 14;
    int r = idx & 16383;
    int k = r >> 7, c = r & 127;
    const float* W = (m == 0) ? W0 : (m == 1) ? W1 : (m == 2) ? W2 : (m == 3) ? W3 : W4;
    float v = W[k * 128 + c];
    u16 h = f2bf(v);
    u16 l = f2bf(v - bf2f(h));
    u16* base = dst + (size_t)m * 32768;
    base[c * 128 + k] = h;
    base[16384 + c * 128 + k] = l;
}

// ---------------- fused SAGE layer via bf16x3 MFMA, A-prefetch pipelined ----------------
// out = gelu(A1@W1 + b1 + A2@W2); A1 packed u32; A2 fp32 (A2F32=1) or packed (0).
// 512 thr = 8 waves; wave = 32 nodes (2 M-tiles); block = 256 nodes (vs r8's 128:
// halves per-node W-staging traffic+barriers, 24 waves/CU at 40KB LDS).
// In-place safety (out may alias A1/A2): wave reads/writes ONLY its own 32 rows;
// prefetch loads are consumed before epilogue stores (wave program order).
template <int A2F32>
__global__ __launch_bounds__(512, 2) void k_sage_mf(const u32* A1, const u16* __restrict__ w1hi,
                                                    const u16* __restrict__ w1lo, const float* __restrict__ b1,
                                                    const void* A2v, const u16* __restrict__ w2hi,
                                                    const u16* __restrict__ w2lo, u32* out) {
    __shared__ u16 lds[4][128][40];
    const int t = threadIdx.x;
    const int lane = t & 63;
    const int w = t >> 6;
    const int l15 = lane & 15;
    const int lg = lane >> 4;
    const int n0 = blockIdx.x * 256 + w * 32;
    f32x4 acc[2][8];
#pragma unroll
    for (int ti = 0; ti < 2; ++ti)
#pragma unroll
        for (int ct = 0; ct < 8; ++ct) acc[ti][ct] = (f32x4){0.f, 0.f, 0.f, 0.f};
    int nA = n0 + l15;
    int nB = n0 + 16 + l15;
    if (nA >= NN) nA = NN - 1;
    if (nB >= NN) nB = NN - 1;
    const u32* a1A = A1 + (size_t)nA * 128;
    const u32* a1B = A1 + (size_t)nB * 128;
    const u32* a2Ap = (const u32*)A2v + (size_t)nA * 128;
    const u32* a2Bp = (const u32*)A2v + (size_t)nB * 128;
    const float* a2Af = (const float*)A2v + (size_t)nA * 128;
    const float* a2Bf = (const float*)A2v + (size_t)nB * 128;
    const int koff = 8 * lg;

    uint4 p1A[2][2], p1B[2][2];
    uint4 p2A[2][2], p2B[2][2];
    float4 f2A[2][2], f2B[2][2];

    {
        const uint4* q;
        q = (const uint4*)(a1A + koff); p1A[0][0] = q[0]; p1A[0][1] = q[1];
        q = (const uint4*)(a1B + koff); p1B[0][0] = q[0]; p1B[0][1] = q[1];
        if (A2F32) {
            const float4* f;
            f = (const float4*)(a2Af + koff); f2A[0][0] = f[0]; f2A[0][1] = f[1];
            f = (const float4*)(a2Bf + koff); f2B[0][0] = f[0]; f2B[0][1] = f[1];
        } else {
            const uint4* q2;
            q2 = (const uint4*)(a2Ap + koff); p2A[0][0] = q2[0]; p2A[0][1] = q2[1];
            q2 = (const uint4*)(a2Bp + koff); p2B[0][0] = q2[0]; p2B[0][1] = q2[1];
        }
    }
#pragma unroll
    for (int kb = 0; kb < 4; ++kb) {
        const int k0 = kb * 32;
        const int cur = kb & 1, nxt = cur ^ 1;
        __syncthreads();
        {   // stage 4 W-slices [128c][32k] bf16: 512 units of 64B, one per thread
            int s = t >> 7, c = t & 127;
            const u16* src = (s == 0) ? w1hi : (s == 1) ? w1lo : (s == 2) ? w2hi : w2lo;
            const uint4* s4 = (const uint4*)(src + (size_t)c * 128 + k0);
            uint4* d4 = (uint4*)&lds[s][c][0];
            d4[0] = s4[0]; d4[1] = s4[1]; d4[2] = s4[2]; d4[3] = s4[3];
        }
        __syncthreads();
        if (kb < 3) {
            const int kn = k0 + 32 + koff;
            const uint4* q;
            q = (const uint4*)(a1A + kn); p1A[nxt][0] = q[0]; p1A[nxt][1] = q[1];
            q = (const uint4*)(a1B + kn); p1B[nxt][0] = q[0]; p1B[nxt][1] = q[1];
            if (A2F32) {
                const float4* f;
                f = (const float4*)(a2Af + kn); f2A[nxt][0] = f[0]; f2A[nxt][1] = f[1];
                f = (const float4*)(a2Bf + kn); f2B[nxt][0] = f[0]; f2B[nxt][1] = f[1];
            } else {
                const uint4* q2;
                q2 = (const uint4*)(a2Ap + kn); p2A[nxt][0] = q2[0]; p2A[nxt][1] = q2[1];
                q2 = (const uint4*)(a2Bp + kn); p2B[nxt][0] = q2[0]; p2B[nxt][1] = q2[1];
            }
        }
        short8 h1A, l1A, h1B, l1B, h2A, l2A, h2B, l2B;
        unpack8(p1A[cur][0], p1A[cur][1], h1A, l1A);
        unpack8(p1B[cur][0], p1B[cur][1], h1B, l1B);
        if (A2F32) {
            cvt8f(f2A[cur][0], f2A[cur][1], h2A, l2A);
            cvt8f(f2B[cur][0], f2B[cur][1], h2B, l2B);
        } else {
            unpack8(p2A[cur][0], p2A[cur][1], h2A, l2A);
            unpack8(p2B[cur][0], p2B[cur][1], h2B, l2B);
        }
#pragma unroll
        for (int ct = 0; ct < 8; ++ct) {
            int c = ct * 16 + l15;
            short8 bh1 = *(const short8*)&lds[0][c][koff];
            short8 bl1 = *(const short8*)&lds[1][c][koff];
            short8 bh2 = *(const short8*)&lds[2][c][koff];
            short8 bl2 = *(const short8*)&lds[3][c][koff];
            acc[0][ct] = MFMA(h1A, bh1, acc[0][ct], 0, 0, 0);
            acc[0][ct] = MFMA(l1A, bh1, acc[0][ct], 0, 0, 0);
            acc[0][ct] = MFMA(h1A, bl1, acc[0][ct], 0, 0, 0);
            acc[0][ct] = MFMA(h2A, bh2, acc[0][ct], 0, 0, 0);
            acc[0][ct] = MFMA(l2A, bh2, acc[0][ct], 0, 0, 0);
            acc[0][ct] = MFMA(h2A, bl2, acc[0][ct], 0, 0, 0);
            acc[1][ct] = MFMA(h1B, bh1, acc[1][ct], 0, 0, 0);
            acc[1][ct] = MFMA(l1B, bh1, acc[1][ct], 0, 0, 0);
            acc[1][ct] = MFMA(h1B, bl1, acc[1][ct], 0, 0, 0);
            acc[1][ct] = MFMA(h2B, bh2, acc[1][ct], 0, 0, 0);
            acc[1][ct] = MFMA(l2B, bh2, acc[1][ct], 0, 0, 0);
            acc[1][ct] = MFMA(h2B, bl2, acc[1][ct], 0, 0, 0);
        }
    }
#pragma unroll
    for (int ti = 0; ti < 2; ++ti) {
#pragma unroll
        for (int ct = 0; ct < 8; ++ct) {
            int c = ct * 16 + l15;
            float bb = b1[c];
#pragma unroll
            for (int r = 0; r < 4; ++r) {
                int node = n0 + ti * 16 + lg * 4 + r;
                if (node < NN) out[(size_t)node * 128 + c] = packf(gelu_f(acc[ti][ct][r] + bb));
            }
        }
    }
}

// ---------------- fused gate via bf16x3 MFMA (packed H input) ----------------
__global__ __launch_bounds__(512, 2) void k_gatef_mf(const u32* __restrict__ H, const u16* __restrict__ wghi,
                                                     const u16* __restrict__ wglo, const float* __restrict__ bg1,
                                                     const float* __restrict__ Wg2, float* __restrict__ gate) {
    __shared__ u16 lds[2][128][40];
    const int t = threadIdx.x;
    const int lane = t & 63;
    const int w = t >> 6;
    const int l15 = lane & 15;
    const int lg = lane >> 4;
    const int n0 = blockIdx.x * 256 + w * 32;
    f32x4 acc[2][8];
#pragma unroll
    for (int ti = 0; ti < 2; ++ti)
#pragma unroll
        for (int ct = 0; ct < 8; ++ct) acc[ti][ct] = (f32x4){0.f, 0.f, 0.f, 0.f};
    int nA = n0 + l15;
    int nB = n0 + 16 + l15;
    if (nA >= NN) nA = NN - 1;
    if (nB >= NN) nB = NN - 1;
    const u32* hA = H + (size_t)nA * 128;
    const u32* hB = H + (size_t)nB * 128;
    const int koff = 8 * lg;
    uint4 pA[2][2], pB[2][2];
    {
        const uint4* q;
        q = (const uint4*)(hA + koff); pA[0][0] = q[0]; pA[0][1] = q[1];
        q = (const uint4*)(hB + koff); pB[0][0] = q[0]; pB[0][1] = q[1];
    }
#pragma unroll
    for (int kb = 0; kb < 4; ++kb) {
        const int k0 = kb * 32;
        const int cur = kb & 1, nxt = cur ^ 1;
        __syncthreads();
        if (t < 256) {  // 2 planes x 128 c
            int s = t >> 7, c = t & 127;
            const u16* src = (s == 0) ? wghi : wglo;
            const uint4* s4 = (const uint4*)(src + (size_t)c * 128 + k0);
            uint4* d4 = (uint4*)&lds[s][c][0];
            d4[0] = s4[0]; d4[1] = s4[1]; d4[2] = s4[2]; d4[3] = s4[3];
        }
        __syncthreads();
        if (kb < 3) {
            const int kn = k0 + 32 + koff;
            const uint4* q;
            q = (const uint4*)(hA + kn); pA[nxt][0] = q[0]; pA[nxt][1] = q[1];
            q = (const uint4*)(hB + kn); pB[nxt][0] = q[0]; pB[nxt][1] = q[1];
        }
        short8 hAh, hAl, hBh, hBl;
        unpack8(pA[cur][0], pA[cur][1], hAh, hAl);
        unpack8(pB[cur][0], pB[cur][1], hBh, hBl);
#pragma unroll
        for (int ct = 0; ct < 8; ++ct) {
            int c = ct * 16 + l15;
            short8 bh = *(const short8*)&lds[0][c][koff];
            short8 bl = *(const short8*)&lds[1][c][koff];
            acc[0][ct] = MFMA(hAh, bh, acc[0][ct], 0, 0, 0);
            acc[0][ct] = MFMA(hAl, bh, acc[0][ct], 0, 0, 0);
            acc[0][ct] = MFMA(hAh, bl, acc[0][ct], 0, 0, 0);
            acc[1][ct] = MFMA(hBh, bh, acc[1][ct], 0, 0, 0);
            acc[1][ct] = MFMA(hBl, bh, acc[1][ct], 0, 0, 0);
            acc[1][ct] = MFMA(hBh, bl, acc[1][ct], 0, 0, 0);
        }
    }
    float p[2][4];
#pragma unroll
    for (int ti = 0; ti < 2; ++ti)
#pragma unroll
        for (int r = 0; r < 4; ++r) p[ti][r] = 0.f;
#pragma unroll
    for (int ct = 0; ct < 8; ++ct) {
        int c = ct * 16 + l15;
        float bb = bg1[c];
        float gv = Wg2[c];
#pragma unroll
        for (int ti = 0; ti < 2; ++ti)
#pragma unroll
            for (int r = 0; r < 4; ++r) p[ti][r] += gelu_f(acc[ti][ct][r] + bb) * gv;
    }
#pragma unroll
    for (int m = 1; m < 16; m <<= 1) {
#pragma unroll
        for (int ti = 0; ti < 2; ++ti)
#pragma unroll
            for (int r = 0; r < 4; ++r) p[ti][r] += __shfl_xor(p[ti][r], m);
    }
    if (l15 == 0) {
#pragma unroll
        for (int ti = 0; ti < 2; ++ti)
#pragma unroll
            for (int r = 0; r < 4; ++r) {
                int node = n0 + ti * 16 + lg * 4 + r;
                if (node < NN) gate[node] = p[ti][r];
            }
    }
}

// ---------------- pooling stage 1 ----------------
__global__ __launch_bounds__(256) void k_pstats(const float* __restrict__ gate, const int* __restrict__ batch,
                                                float* __restrict__ gm, float* __restrict__ gden) {
    int g = blockIdx.x;
    int lo = 0, hi = NN;
    while (lo < hi) { int mid = (lo + hi) >> 1; if (batch[mid] < g) lo = mid + 1; else hi = mid; }
    int start = lo;
    lo = start; hi = NN;
    while (lo < hi) { int mid = (lo + hi) >> 1; if (batch[mid] < g + 1) lo = mid + 1; else hi = mid; }
    int endp = lo;

    __shared__ float red[256];
    int tid = threadIdx.x;

    float m = -1e30f;
    for (int i = start + tid; i < endp; i += 256) m = fmaxf(m, gate[i]);
    red[tid] = m;
    __syncthreads();
    for (int off = 128; off; off >>= 1) {
        if (tid < off) red[tid] = fmaxf(red[tid], red[tid + off]);
        __syncthreads();
    }
    m = red[0];
    __syncthreads();

    float s = 0.f;
    for (int i = start + tid; i < endp; i += 256) s += expf(gate[i] - m);
    red[tid] = s;
    __syncthreads();
    for (int off = 128; off; off >>= 1) {
        if (tid < off) red[tid] += red[tid + off];
        __syncthreads();
    }
    if (tid == 0) { gm[g] = m; gden[g] = red[0]; }
}

// ---------------- pooling stage 2 (packed H) ----------------
__global__ __launch_bounds__(256) void k_pacc(const u32* __restrict__ H, const float* __restrict__ gate,
                                              const int* __restrict__ batch, const float* __restrict__ gm,
                                              const float* __restrict__ gden, float* __restrict__ gacc) {
    int c = threadIdx.x & 127;
    int h = threadIdx.x >> 7;
    int n0 = blockIdx.x * 128;
    int nend = n0 + 128;
    if (nend > NN) nend = NN;
    int i = n0 + h;
    if (i >= nend) return;
    int cur = batch[i];
    float m = gm[cur], invd = 1.0f / gden[cur];
    float acc = 0.f;
    for (; i < nend; i += 2) {
        int gi = batch[i];
        if (gi != cur) {
            atomicAdd(&gacc[cur * 128 + c], acc * invd);
            acc = 0.f;
            cur = gi;
            m = gm[cur];
            invd = 1.0f / gden[cur];
        }
        acc = fmaf(expf(gate[i] - m), unpackf(H[(size_t)i * 128 + c]), acc);
    }
    atomicAdd(&gacc[cur * 128 + c], acc * invd);
}

// ---------------- head ----------------
__global__ __launch_bounds__(64) void k_head(const float* __restrict__ gacc, const float* __restrict__ Wh,
                                             const float* __restrict__ bh, float* __restrict__ out) {
    int g = blockIdx.x;
    int l = threadIdx.x;
    float v = gacc[g * 128 + l] * Wh[l] + gacc[g * 128 + 64 + l] * Wh[64 + l];
#pragma unroll
    for (int m = 1; m < 64; m <<= 1) v += __shfl_xor(v, m);
    if (l == 0) out[g] = v + bh[0];
}

extern "C" void kernel_launch(void* const* d_in, const int* in_sizes, int n_in,
                              void* d_out, int out_size, void* d_ws, size_t ws_size,
                              hipStream_t stream) {
    (void)in_sizes; (void)n_in; (void)out_size; (void)ws_size;
    const float* x   = (const float*)d_in[0];
    const int*  ei   = (const int*)d_in[1];
    const int*  batch= (const int*)d_in[2];
    const float* Wl0 = (const float*)d_in[3];
    const float* bl0 = (const float*)d_in[4];
    const float* Wr0 = (const float*)d_in[5];
    const float* Wl1 = (const float*)d_in[6];
    const float* bl1 = (const float*)d_in[7];
    const float* Wr1 = (const float*)d_in[8];
    const float* Wg1 = (const float*)d_in[9];
    const float* bg1 = (const float*)d_in[10];
    const float* Wg2 = (const float*)d_in[11];
    const float* Wh  = (const float*)d_in[13];
    const float* bh  = (const float*)d_in[14];
    float* out = (float*)d_out;

    const int* srcp = ei;
    const int* dstp = ei + NE;

    char* w = (char*)d_ws;
    size_t off = 0;
    auto alloc = [&](size_t bytes) { void* p = w + off; off += (bytes + 255) & ~(size_t)255; return p; };
    u32* AGG   = (u32*)alloc((size_t)NN * 128 * 4);  // packed agg / h2 (in-place)
    u32* H1    = (u32*)alloc((size_t)NN * 128 * 4);  // packed h1
    float* gate  = (float*)alloc((size_t)NN * 4);
    int* cnt     = (int*)alloc((size_t)NN * 4);
    int* rowp    = (int*)alloc((size_t)(NN + 1) * 4);
    int* fill    = (int*)alloc((size_t)NN * 4);
    int* cidx    = (int*)alloc((size_t)NE * 4);
    int* blksum  = (int*)alloc(128 * 4);
    int* blkoff  = (int*)alloc(128 * 4);
    float* gm    = (float*)alloc(NG * 4);
    float* gden  = (float*)alloc(NG * 4);
    float* gacc  = (float*)alloc((size_t)NG * 128 * 4);
    u16* wt      = (u16*)alloc((size_t)5 * 32768 * 2);   // 5 mats x (hi|lo) [c][k] bf16

    hipMemsetAsync(cnt, 0, (size_t)NN * 4, stream);
    hipMemsetAsync(fill, 0, (size_t)NN * 4, stream);
    hipMemsetAsync(gacc, 0, (size_t)NG * 128 * 4, stream);

    // weight transpose + bf16 hi/lo split (mat order: Wl0, Wr0, Wl1, Wr1, Wg1)
    k_cvtw<<<320, 256, 0, stream>>>(Wl0, Wr0, Wl1, Wr1, Wg1, wt);

    // CSR build (reused by both layers)
    k_hist<<<(NE + 255) / 256, 256, 0, stream>>>(dstp, cnt);
    int nb = (NN + SB - 1) / SB;
    k_scan1<<<nb, SB, 0, stream>>>(cnt, rowp, blksum);
    k_scan2<<<1, 128, 0, stream>>>(blksum, blkoff, nb);
    k_scan3<<<(NN + 1 + 255) / 256, 256, 0, stream>>>(rowp, blkoff);
    k_scatter<<<(NE + 255) / 256, 256, 0, stream>>>(srcp, dstp, rowp, fill, cidx);

    int gs = (NN + 255) / 256;           // 391 GEMM blocks (256-node tiles, 512 thr)
    int ga = (NN * 32 + 255) / 256;      // k_agg: 32 lanes per node
    u16* Wl0hi = wt;
    u16* Wl0lo = wt + 16384;
    u16* Wr0hi = wt + 32768;
    u16* Wr0lo = wt + 49152;
    u16* Wl1hi = wt + 65536;
    u16* Wl1lo = wt + 81920;
    u16* Wr1hi = wt + 98304;
    u16* Wr1lo = wt + 114688;
    u16* Wg1hi = wt + 131072;
    u16* Wg1lo = wt + 147456;
    // layer 0: agg from fp32 x; root A2 = fp32 x
    k_agg<0><<<ga, 256, 0, stream>>>(x, rowp, cidx, AGG);
    k_sage_mf<1><<<gs, 512, 0, stream>>>(AGG, Wl0hi, Wl0lo, bl0, x, Wr0hi, Wr0lo, H1);
    // layer 1: agg from packed h1; root A2 = packed h1; h2 in-place over AGG
    k_agg<1><<<ga, 256, 0, stream>>>(H1, rowp, cidx, AGG);
    k_sage_mf<0><<<gs, 512, 0, stream>>>(AGG, Wl1hi, Wl1lo, bl1, H1, Wr1hi, Wr1lo, AGG);
    // gate + pool + head (H = packed h2 in AGG)
    k_gatef_mf<<<gs, 512, 0, stream>>>(AGG, Wg1hi, Wg1lo, bg1, Wg2, gate);
    k_pstats<<<NG, 256, 0, stream>>>(gate, batch, gm, gden);
    k_pacc<<<(NN + 127) / 128, 256, 0, stream>>>(AGG, gate, batch, gm, gden, gacc);
    k_head<<<NG, 64, 0, stream>>>(gacc, Wh, bh, out);
}